// Round 1
// baseline (3294.636 us; speedup 1.0000x reference)
//
#include <hip/hip_runtime.h>
#include <math.h>

#define N_NODES 100000
#define N_EDGES 800000
#define FDIM 256
#define HEADS 8
#define CDIM 32
#define OUTF 128

// ---------------- GEMM: out[r, m] = sum_k A[r,k] * W[k,m] + bias[m] ----------------
// K fixed at 256. blockDim.x == M. 8 rows per block, A rows staged in LDS.
template <int M>
__global__ void gemm_bias(const float* __restrict__ A, const float* __restrict__ W,
                          const float* __restrict__ bias, float* __restrict__ out,
                          int nrows) {
    const int ROWS = 8;
    __shared__ float As[ROWS][FDIM];
    int row0 = blockIdx.x * ROWS;
    int tid = threadIdx.x;

    for (int i = tid; i < ROWS * FDIM; i += M) {
        int r = i / FDIM, c = i % FDIM;
        int gr = row0 + r;
        As[r][c] = (gr < nrows) ? A[(size_t)gr * FDIM + c] : 0.f;
    }
    __syncthreads();

    float acc[ROWS];
#pragma unroll
    for (int r = 0; r < ROWS; r++) acc[r] = 0.f;

#pragma unroll 4
    for (int k = 0; k < FDIM; k++) {
        float w = W[(size_t)k * M + tid];
#pragma unroll
        for (int r = 0; r < ROWS; r++) acc[r] += As[r][k] * w;
    }
    float b = bias[tid];
#pragma unroll
    for (int r = 0; r < ROWS; r++) {
        int gr = row0 + r;
        if (gr < nrows) out[(size_t)gr * M + tid] = acc[r] + b;
    }
}

// ---------------- Edge logits: ex[e,h] = exp(sum_c lrelu(xl[src]+xr[dst]) * att[h,c]) ----
// One 64-lane wave per edge. denom[dst,h] += ex via atomics.
__global__ void edge_logits(const float* __restrict__ xl, const float* __restrict__ xr,
                            const int* __restrict__ srcA, const int* __restrict__ dstA,
                            const float* __restrict__ att, float* __restrict__ ex,
                            float* __restrict__ denom) {
    int gtid = blockIdx.x * blockDim.x + threadIdx.x;
    int wave = gtid >> 6;
    int lane = threadIdx.x & 63;
    int nwaves = (gridDim.x * blockDim.x) >> 6;

    float a0 = att[lane];
    float a1 = att[64 + lane];
    float a2 = att[128 + lane];
    float a3 = att[192 + lane];

    for (int e = wave; e < N_EDGES; e += nwaves) {
        int s = srcA[e], d = dstA[e];
        const float* pl = xl + (size_t)s * FDIM;
        const float* pr = xr + (size_t)d * FDIM;
        float part[4];
#pragma unroll
        for (int i = 0; i < 4; i++) {
            float v = pl[i * 64 + lane] + pr[i * 64 + lane];
            v = v > 0.f ? v : 0.2f * v;
            float a = (i == 0) ? a0 : (i == 1) ? a1 : (i == 2) ? a2 : a3;
            part[i] = v * a;
        }
        // reduce over c (32-lane halves). xor offsets < 32 never cross the half boundary.
#pragma unroll
        for (int i = 0; i < 4; i++) {
            float p = part[i];
            p += __shfl_xor(p, 16);
            p += __shfl_xor(p, 8);
            p += __shfl_xor(p, 4);
            p += __shfl_xor(p, 2);
            p += __shfl_xor(p, 1);
            part[i] = p;
        }
        if ((lane & 31) == 0) {
            int hi = lane >> 5;
#pragma unroll
            for (int i = 0; i < 4; i++) {
                int h = i * 2 + hi;
                float v = expf(part[i]);
                ex[(size_t)e * HEADS + h] = v;
                atomicAdd(&denom[(size_t)d * HEADS + h], v);
            }
        }
    }
}

// ---------------- Edge aggregate: out[dst, h, c] += xl[src, h, c] * alpha[e, h] --------
__global__ void edge_aggregate(const float* __restrict__ xl,
                               const int* __restrict__ srcA, const int* __restrict__ dstA,
                               const float* __restrict__ ex, const float* __restrict__ denom,
                               float* __restrict__ out) {
    int gtid = blockIdx.x * blockDim.x + threadIdx.x;
    int wave = gtid >> 6;
    int lane = threadIdx.x & 63;
    int nwaves = (gridDim.x * blockDim.x) >> 6;

    for (int e = wave; e < N_EDGES; e += nwaves) {
        int s = srcA[e], d = dstA[e];
        const float* pl = xl + (size_t)s * FDIM;
        float* po = out + (size_t)d * FDIM;
#pragma unroll
        for (int i = 0; i < 4; i++) {
            int idx = i * 64 + lane;
            int h = idx >> 5;
            float alpha = ex[(size_t)e * HEADS + h] / (denom[(size_t)d * HEADS + h] + 1e-16f);
            atomicAdd(&po[idx], pl[idx] * alpha);
        }
    }
}

// ---------------- BatchNorm stats: per-column sum / sumsq over rows --------------------
__global__ void bn_stats(const float* __restrict__ X, float* __restrict__ sum,
                         float* __restrict__ sumsq, int nrows) {
    int col = threadIdx.x;  // 256 threads
    float s = 0.f, ss = 0.f;
    for (int r = blockIdx.x; r < nrows; r += gridDim.x) {
        float v = X[(size_t)r * FDIM + col];
        s += v;
        ss += v * v;
    }
    atomicAdd(&sum[col], s);
    atomicAdd(&sumsq[col], ss);
}

__global__ void bn_finalize(const float* __restrict__ sum, const float* __restrict__ sumsq,
                            const float* __restrict__ gamma, const float* __restrict__ beta,
                            float* __restrict__ scale, float* __restrict__ shift) {
    int c = threadIdx.x;
    float mean = sum[c] * (1.f / N_NODES);
    float var = sumsq[c] * (1.f / N_NODES) - mean * mean;
    float sc = gamma[c] * rsqrtf(var + 1e-5f);
    scale[c] = sc;
    shift[c] = beta[c] - mean * sc;
}

__global__ void bn_apply_elu(float* __restrict__ X, const float* __restrict__ scale,
                             const float* __restrict__ shift, int n) {
    int i = blockIdx.x * blockDim.x + threadIdx.x;
    int stride = gridDim.x * blockDim.x;
    for (; i < n; i += stride) {
        int c = i & (FDIM - 1);
        float v = X[i] * scale[c] + shift[c];
        X[i] = v > 0.f ? v : expf(v) - 1.f;
    }
}

// ---------------- Row L2 normalize (rows of 128) --------------------------------------
__global__ void l2norm(float* __restrict__ Y, int nrows) {
    int gtid = blockIdx.x * blockDim.x + threadIdx.x;
    int wave = gtid >> 6;
    int lane = threadIdx.x & 63;
    int nwaves = (gridDim.x * blockDim.x) >> 6;
    for (int r = wave; r < nrows; r += nwaves) {
        float v0 = Y[(size_t)r * OUTF + lane];
        float v1 = Y[(size_t)r * OUTF + 64 + lane];
        float ss = v0 * v0 + v1 * v1;
        ss += __shfl_xor(ss, 32);
        ss += __shfl_xor(ss, 16);
        ss += __shfl_xor(ss, 8);
        ss += __shfl_xor(ss, 4);
        ss += __shfl_xor(ss, 2);
        ss += __shfl_xor(ss, 1);
        float inv = 1.f / fmaxf(sqrtf(ss), 1e-12f);
        Y[(size_t)r * OUTF + lane] = v0 * inv;
        Y[(size_t)r * OUTF + 64 + lane] = v1 * inv;
    }
}

extern "C" void kernel_launch(void* const* d_in, const int* in_sizes, int n_in,
                              void* d_out, int out_size, void* d_ws, size_t ws_size,
                              hipStream_t stream) {
    const float* x     = (const float*)d_in[0];
    const int*   ei    = (const int*)d_in[1];
    const float* Wl1   = (const float*)d_in[2];
    const float* bl1   = (const float*)d_in[3];
    const float* Wr1   = (const float*)d_in[4];
    const float* br1   = (const float*)d_in[5];
    const float* att1  = (const float*)d_in[6];
    // d_in[7] = bias1 : cancels exactly inside batchnorm (mean subtraction) -> skipped
    const float* gamma1 = (const float*)d_in[8];
    const float* beta1  = (const float*)d_in[9];
    const float* Wl2   = (const float*)d_in[10];
    const float* bl2   = (const float*)d_in[11];
    const float* Wr2   = (const float*)d_in[12];
    const float* br2   = (const float*)d_in[13];
    const float* att2  = (const float*)d_in[14];
    // d_in[15] = bias2 : cancels inside batchnorm -> skipped
    const float* gamma2 = (const float*)d_in[16];
    const float* beta2  = (const float*)d_in[17];
    const float* Wfc   = (const float*)d_in[18];
    const float* bfc   = (const float*)d_in[19];

    const int* srcA = ei;
    const int* dstA = ei + N_EDGES;

    float* ws = (float*)d_ws;
    float* A   = ws;                          // xl  [N, 256]
    float* B   = A + (size_t)N_NODES * FDIM;  // xr  [N, 256]
    float* O   = B + (size_t)N_NODES * FDIM;  // out / h (in-place) [N, 256]
    float* EX  = O + (size_t)N_NODES * FDIM;  // [E, 8]
    float* DEN = EX + (size_t)N_EDGES * HEADS;  // [N, 8]
    float* SUM = DEN + (size_t)N_NODES * HEADS; // [256]
    float* SQ  = SUM + FDIM;                  // [256]
    float* SC  = SQ + FDIM;                   // [256]
    float* SH  = SC + FDIM;                   // [256]

    int gemm_grid = (N_NODES + 7) / 8;

    // ---------------- Layer 1 ----------------
    gemm_bias<256><<<gemm_grid, 256, 0, stream>>>(x, Wl1, bl1, A, N_NODES);
    gemm_bias<256><<<gemm_grid, 256, 0, stream>>>(x, Wr1, br1, B, N_NODES);

    hipMemsetAsync(DEN, 0, (size_t)N_NODES * HEADS * sizeof(float), stream);
    edge_logits<<<2048, 256, 0, stream>>>(A, B, srcA, dstA, att1, EX, DEN);

    hipMemsetAsync(O, 0, (size_t)N_NODES * FDIM * sizeof(float), stream);
    edge_aggregate<<<2048, 256, 0, stream>>>(A, srcA, dstA, EX, DEN, O);

    hipMemsetAsync(SUM, 0, 2 * FDIM * sizeof(float), stream);
    bn_stats<<<1024, 256, 0, stream>>>(O, SUM, SQ, N_NODES);
    bn_finalize<<<1, 256, 0, stream>>>(SUM, SQ, gamma1, beta1, SC, SH);
    bn_apply_elu<<<2048, 256, 0, stream>>>(O, SC, SH, N_NODES * FDIM);

    // ---------------- Layer 2 ----------------
    gemm_bias<256><<<gemm_grid, 256, 0, stream>>>(O, Wl2, bl2, A, N_NODES);
    gemm_bias<256><<<gemm_grid, 256, 0, stream>>>(O, Wr2, br2, B, N_NODES);

    hipMemsetAsync(DEN, 0, (size_t)N_NODES * HEADS * sizeof(float), stream);
    edge_logits<<<2048, 256, 0, stream>>>(A, B, srcA, dstA, att2, EX, DEN);

    hipMemsetAsync(O, 0, (size_t)N_NODES * FDIM * sizeof(float), stream);
    edge_aggregate<<<2048, 256, 0, stream>>>(A, srcA, dstA, EX, DEN, O);

    hipMemsetAsync(SUM, 0, 2 * FDIM * sizeof(float), stream);
    bn_stats<<<1024, 256, 0, stream>>>(O, SUM, SQ, N_NODES);
    bn_finalize<<<1, 256, 0, stream>>>(SUM, SQ, gamma2, beta2, SC, SH);
    bn_apply_elu<<<2048, 256, 0, stream>>>(O, SC, SH, N_NODES * FDIM);

    // ---------------- FC + L2 normalize ----------------
    gemm_bias<128><<<gemm_grid, 128, 0, stream>>>(O, Wfc, bfc, (float*)d_out, N_NODES);
    l2norm<<<2048, 256, 0, stream>>>((float*)d_out, N_NODES);
}

// Round 2
// 2148.169 us; speedup vs baseline: 1.5337x; 1.5337x over previous
//
#include <hip/hip_runtime.h>
#include <math.h>

#define N_NODES 100000
#define N_EDGES 800000
#define FDIM 256
#define HEADS 8
#define CDIM 32
#define OUTF 128

// ---------------- GEMM: out[r, m] = sum_k A[r,k] * W[k,m] + bias[m] ----------------
template <int M>
__global__ void gemm_bias(const float* __restrict__ A, const float* __restrict__ W,
                          const float* __restrict__ bias, float* __restrict__ out,
                          int nrows) {
    const int ROWS = 8;
    __shared__ float As[ROWS][FDIM];
    int row0 = blockIdx.x * ROWS;
    int tid = threadIdx.x;

    for (int i = tid; i < ROWS * FDIM; i += M) {
        int r = i / FDIM, c = i % FDIM;
        int gr = row0 + r;
        As[r][c] = (gr < nrows) ? A[(size_t)gr * FDIM + c] : 0.f;
    }
    __syncthreads();

    float acc[ROWS];
#pragma unroll
    for (int r = 0; r < ROWS; r++) acc[r] = 0.f;

#pragma unroll 4
    for (int k = 0; k < FDIM; k++) {
        float w = W[(size_t)k * M + tid];
#pragma unroll
        for (int r = 0; r < ROWS; r++) acc[r] += As[r][k] * w;
    }
    float b = bias[tid];
#pragma unroll
    for (int r = 0; r < ROWS; r++) {
        int gr = row0 + r;
        if (gr < nrows) out[(size_t)gr * M + tid] = acc[r] + b;
    }
}

// ---------------- CSR build ----------------
__global__ void count_deg(const int* __restrict__ dstA, int* __restrict__ deg) {
    int i = blockIdx.x * blockDim.x + threadIdx.x;
    int stride = gridDim.x * blockDim.x;
    for (; i < N_EDGES; i += stride) atomicAdd(&deg[dstA[i]], 1);
}

// single block, 1024 threads: exclusive scan of deg -> rowstart (+ cursor copy)
__global__ void scan_deg(const int* __restrict__ deg, int* __restrict__ rowstart,
                         int* __restrict__ cursor) {
    const int T = 1024;
    const int CHUNK = (N_NODES + T - 1) / T;  // 98
    __shared__ int part[T];
    int t = threadIdx.x;
    int lo = t * CHUNK;
    int hi = lo + CHUNK; if (hi > N_NODES) hi = N_NODES;
    int s = 0;
    for (int i = lo; i < hi; i++) s += deg[i];
    part[t] = s;
    __syncthreads();
    for (int off = 1; off < T; off <<= 1) {
        int v = 0;
        if (t >= off) v = part[t - off];
        __syncthreads();
        if (t >= off) part[t] += v;
        __syncthreads();
    }
    int run = (t == 0) ? 0 : part[t - 1];
    for (int i = lo; i < hi; i++) {
        rowstart[i] = run;
        cursor[i] = run;
        run += deg[i];
    }
    if (t == T - 1) rowstart[N_NODES] = part[T - 1];
}

__global__ void fill_csr(const int* __restrict__ srcA, const int* __restrict__ dstA,
                         int* __restrict__ cursor, int* __restrict__ csr_src) {
    int i = blockIdx.x * blockDim.x + threadIdx.x;
    int stride = gridDim.x * blockDim.x;
    for (; i < N_EDGES; i += stride) {
        int pos = atomicAdd(&cursor[dstA[i]], 1);
        csr_src[pos] = srcA[i];
    }
}

// ---------------- Fused GATv2 edge phase: one wave per destination node ----------------
// out[n, :] = sum_{e in in(n)} exp(logit_e) * xl[src_e, :] / (sum exp(logit_e) + 1e-16)
__global__ void gat_fused(const float* __restrict__ xl, const float* __restrict__ xr,
                          const int* __restrict__ rowstart, const int* __restrict__ csr_src,
                          const float* __restrict__ att, float* __restrict__ out) {
    int wid = (blockIdx.x * blockDim.x + threadIdx.x) >> 6;
    int lane = threadIdx.x & 63;
    if (wid >= N_NODES) return;

    float xrv[4], attv[4], acc[4], den[4];
#pragma unroll
    for (int i = 0; i < 4; i++) {
        xrv[i] = xr[(size_t)wid * FDIM + i * 64 + lane];
        attv[i] = att[i * 64 + lane];
        acc[i] = 0.f;
        den[i] = 0.f;
    }

    int jb = rowstart[wid], je = rowstart[wid + 1];
    for (int j = jb; j < je; ++j) {
        int s = csr_src[j];
        const float* pl = xl + (size_t)s * FDIM;
        float xv[4], p[4];
#pragma unroll
        for (int i = 0; i < 4; i++) {
            xv[i] = pl[i * 64 + lane];
            float v = xv[i] + xrv[i];
            v = v > 0.f ? v : 0.2f * v;
            p[i] = v * attv[i];
        }
        // per-head reduction: head = (i*64+lane)>>5, contiguous 32-lane halves
#pragma unroll
        for (int i = 0; i < 4; i++) {
            float q = p[i];
            q += __shfl_xor(q, 16);
            q += __shfl_xor(q, 8);
            q += __shfl_xor(q, 4);
            q += __shfl_xor(q, 2);
            q += __shfl_xor(q, 1);
            float ex = expf(q);
            den[i] += ex;
            acc[i] += ex * xv[i];
        }
    }
#pragma unroll
    for (int i = 0; i < 4; i++)
        out[(size_t)wid * FDIM + i * 64 + lane] = acc[i] / (den[i] + 1e-16f);
}

// ---------------- BatchNorm ----------------
__global__ void bn_stats(const float* __restrict__ X, float* __restrict__ sum,
                         float* __restrict__ sumsq, int nrows) {
    int col = threadIdx.x;  // 256 threads
    float s = 0.f, ss = 0.f;
    for (int r = blockIdx.x; r < nrows; r += gridDim.x) {
        float v = X[(size_t)r * FDIM + col];
        s += v;
        ss += v * v;
    }
    atomicAdd(&sum[col], s);
    atomicAdd(&sumsq[col], ss);
}

__global__ void bn_finalize(const float* __restrict__ sum, const float* __restrict__ sumsq,
                            const float* __restrict__ gamma, const float* __restrict__ beta,
                            float* __restrict__ scale, float* __restrict__ shift) {
    int c = threadIdx.x;
    float mean = sum[c] * (1.f / N_NODES);
    float var = sumsq[c] * (1.f / N_NODES) - mean * mean;
    float sc = gamma[c] * rsqrtf(var + 1e-5f);
    scale[c] = sc;
    shift[c] = beta[c] - mean * sc;
}

__global__ void bn_apply_elu(float* __restrict__ X, const float* __restrict__ scale,
                             const float* __restrict__ shift, int n) {
    int i = blockIdx.x * blockDim.x + threadIdx.x;
    int stride = gridDim.x * blockDim.x;
    for (; i < n; i += stride) {
        int c = i & (FDIM - 1);
        float v = X[i] * scale[c] + shift[c];
        X[i] = v > 0.f ? v : expf(v) - 1.f;
    }
}

// ---------------- Row L2 normalize (rows of 128) ----------------
__global__ void l2norm(float* __restrict__ Y, int nrows) {
    int gtid = blockIdx.x * blockDim.x + threadIdx.x;
    int wave = gtid >> 6;
    int lane = threadIdx.x & 63;
    int nwaves = (gridDim.x * blockDim.x) >> 6;
    for (int r = wave; r < nrows; r += nwaves) {
        float v0 = Y[(size_t)r * OUTF + lane];
        float v1 = Y[(size_t)r * OUTF + 64 + lane];
        float ss = v0 * v0 + v1 * v1;
        ss += __shfl_xor(ss, 32);
        ss += __shfl_xor(ss, 16);
        ss += __shfl_xor(ss, 8);
        ss += __shfl_xor(ss, 4);
        ss += __shfl_xor(ss, 2);
        ss += __shfl_xor(ss, 1);
        float inv = 1.f / fmaxf(sqrtf(ss), 1e-12f);
        Y[(size_t)r * OUTF + lane] = v0 * inv;
        Y[(size_t)r * OUTF + 64 + lane] = v1 * inv;
    }
}

extern "C" void kernel_launch(void* const* d_in, const int* in_sizes, int n_in,
                              void* d_out, int out_size, void* d_ws, size_t ws_size,
                              hipStream_t stream) {
    const float* x     = (const float*)d_in[0];
    const int*   ei    = (const int*)d_in[1];
    const float* Wl1   = (const float*)d_in[2];
    const float* bl1   = (const float*)d_in[3];
    const float* Wr1   = (const float*)d_in[4];
    const float* br1   = (const float*)d_in[5];
    const float* att1  = (const float*)d_in[6];
    // d_in[7] = bias1 : cancels exactly inside batchnorm -> skipped
    const float* gamma1 = (const float*)d_in[8];
    const float* beta1  = (const float*)d_in[9];
    const float* Wl2   = (const float*)d_in[10];
    const float* bl2   = (const float*)d_in[11];
    const float* Wr2   = (const float*)d_in[12];
    const float* br2   = (const float*)d_in[13];
    const float* att2  = (const float*)d_in[14];
    // d_in[15] = bias2 : cancels inside batchnorm -> skipped
    const float* gamma2 = (const float*)d_in[16];
    const float* beta2  = (const float*)d_in[17];
    const float* Wfc   = (const float*)d_in[18];
    const float* bfc   = (const float*)d_in[19];

    const int* srcA = ei;
    const int* dstA = ei + N_EDGES;

    float* ws = (float*)d_ws;
    float* A   = ws;                          // xl  [N, 256]
    float* B   = A + (size_t)N_NODES * FDIM;  // xr  [N, 256]
    float* O   = B + (size_t)N_NODES * FDIM;  // h   [N, 256]
    float* SUM = O + (size_t)N_NODES * FDIM;  // [256]
    float* SQ  = SUM + FDIM;
    float* SC  = SQ + FDIM;
    float* SH  = SC + FDIM;
    int* DEG      = (int*)(SH + FDIM);        // [N]
    int* ROWSTART = DEG + N_NODES;            // [N+1]
    int* CURSOR   = ROWSTART + N_NODES + 1;   // [N]
    int* CSR      = CURSOR + N_NODES;         // [E]

    int gemm_grid = (N_NODES + 7) / 8;
    int gat_grid = (N_NODES + 3) / 4;  // 4 waves (nodes) per 256-thread block

    // ---------------- CSR build (edge_index only, shared by both layers) ----------------
    hipMemsetAsync(DEG, 0, (size_t)N_NODES * sizeof(int), stream);
    count_deg<<<2048, 256, 0, stream>>>(dstA, DEG);
    scan_deg<<<1, 1024, 0, stream>>>(DEG, ROWSTART, CURSOR);
    fill_csr<<<2048, 256, 0, stream>>>(srcA, dstA, CURSOR, CSR);

    // ---------------- Layer 1 ----------------
    gemm_bias<256><<<gemm_grid, 256, 0, stream>>>(x, Wl1, bl1, A, N_NODES);
    gemm_bias<256><<<gemm_grid, 256, 0, stream>>>(x, Wr1, br1, B, N_NODES);

    gat_fused<<<gat_grid, 256, 0, stream>>>(A, B, ROWSTART, CSR, att1, O);

    hipMemsetAsync(SUM, 0, 2 * FDIM * sizeof(float), stream);
    bn_stats<<<1024, 256, 0, stream>>>(O, SUM, SQ, N_NODES);
    bn_finalize<<<1, 256, 0, stream>>>(SUM, SQ, gamma1, beta1, SC, SH);
    bn_apply_elu<<<2048, 256, 0, stream>>>(O, SC, SH, N_NODES * FDIM);

    // ---------------- Layer 2 ----------------
    gemm_bias<256><<<gemm_grid, 256, 0, stream>>>(O, Wl2, bl2, A, N_NODES);
    gemm_bias<256><<<gemm_grid, 256, 0, stream>>>(O, Wr2, br2, B, N_NODES);

    gat_fused<<<gat_grid, 256, 0, stream>>>(A, B, ROWSTART, CSR, att2, O);

    hipMemsetAsync(SUM, 0, 2 * FDIM * sizeof(float), stream);
    bn_stats<<<1024, 256, 0, stream>>>(O, SUM, SQ, N_NODES);
    bn_finalize<<<1, 256, 0, stream>>>(SUM, SQ, gamma2, beta2, SC, SH);
    bn_apply_elu<<<2048, 256, 0, stream>>>(O, SC, SH, N_NODES * FDIM);

    // ---------------- FC + L2 normalize ----------------
    gemm_bias<128><<<gemm_grid, 128, 0, stream>>>(O, Wfc, bfc, (float*)d_out, N_NODES);
    l2norm<<<2048, 256, 0, stream>>>((float*)d_out, N_NODES);
}

// Round 4
// 1278.323 us; speedup vs baseline: 2.5773x; 1.6805x over previous
//
#include <hip/hip_runtime.h>
#include <math.h>

#define N_NODES 100000
#define N_EDGES 800000
#define NPAD    100096   // 782 * 128
#define FDIM 256
#define HEADS 8
#define CDIM 32
#define OUTF 128

typedef short  s16x8 __attribute__((ext_vector_type(8)));
typedef float  f32x4 __attribute__((ext_vector_type(4)));
typedef unsigned short u16;

__device__ __forceinline__ u16 f2bf(float f) {
    unsigned u = __float_as_uint(f);
    unsigned r = (u + 0x7fff + ((u >> 16) & 1)) >> 16;
    return (u16)r;
}
__device__ __forceinline__ float bf2f(u16 h) {
    return __uint_as_float(((unsigned)h) << 16);
}

__device__ __forceinline__ void gload_lds16(const void* g, void* l) {
    __builtin_amdgcn_global_load_lds((const __attribute__((address_space(1))) void*)g,
                                     (__attribute__((address_space(3))) void*)l, 16, 0, 0);
}

// ---------------- split f32 -> bf16 hi/lo (pad region zeroed) ----------------
__global__ void split_hilo(const float* __restrict__ src, int n_valid4, int n_pad4,
                           u16* __restrict__ hi, u16* __restrict__ lo) {
    int i = blockIdx.x * blockDim.x + threadIdx.x;
    int stride = gridDim.x * blockDim.x;
    for (; i < n_pad4; i += stride) {
        f32x4 v = {0.f, 0.f, 0.f, 0.f};
        if (i < n_valid4) v = ((const f32x4*)src)[i];
        u16 h[4], l[4];
#pragma unroll
        for (int j = 0; j < 4; j++) {
            float f = v[j];
            h[j] = f2bf(f);
            l[j] = f2bf(f - bf2f(h[j]));
        }
        ((ushort4*)hi)[i] = make_ushort4(h[0], h[1], h[2], h[3]);
        ((ushort4*)lo)[i] = make_ushort4(l[0], l[1], l[2], l[3]);
    }
}

// ---------------- W prep: transpose + concat + split ----------------
__global__ void prep_w_layer(const float* __restrict__ Wl, const float* __restrict__ Wr,
                             u16* __restrict__ WtH, u16* __restrict__ WtL) {
    int idx = blockIdx.x * blockDim.x + threadIdx.x;
    if (idx >= 512 * 256) return;
    int n = idx >> 8, k = idx & 255;
    float w = (n < 256) ? Wl[k * 256 + n] : Wr[k * 256 + (n - 256)];
    u16 h = f2bf(w);
    WtH[idx] = h;
    WtL[idx] = f2bf(w - bf2f(h));
}

__global__ void prep_w_fc(const float* __restrict__ Wfc,
                          u16* __restrict__ WtH, u16* __restrict__ WtL) {
    int idx = blockIdx.x * blockDim.x + threadIdx.x;
    if (idx >= 128 * 256) return;
    int n = idx >> 8, k = idx & 255;
    float w = Wfc[k * 128 + n];
    u16 h = f2bf(w);
    WtH[idx] = h;
    WtL[idx] = f2bf(w - bf2f(h));
}

// ---------------- 3-term split-precision bf16 MFMA GEMM ----------------
// C = A@W + bias via Ah@Wh + Al@Wh + Ah@Wl. Cols <256 -> C0, else C1.
// A*: bf16 [NPAD][256]. Wt*: bf16 [NB][256] (W transposed). 128x128 tile, BK=64.
__global__ __launch_bounds__(256) void gemm3(
        const u16* __restrict__ Ah, const u16* __restrict__ Al,
        const u16* __restrict__ WtH, const u16* __restrict__ WtL,
        const float* __restrict__ bias0, const float* __restrict__ bias1,
        float* __restrict__ C0, float* __restrict__ C1, int ldc, int M) {
    __shared__ __align__(16) u16 lA[128 * 64];
    __shared__ __align__(16) u16 lB[128 * 64];

    int tid = threadIdx.x;
    int wid = tid >> 6, lane = tid & 63;
    int wm = wid >> 1, wn = wid & 1;
    int m0 = blockIdx.x * 128, n0 = blockIdx.y * 128;
    int lr = lane & 15, lk = lane >> 4;

    f32x4 acc[4][4] = {};

#pragma unroll 1
    for (int seg = 0; seg < 3; seg++) {
        const u16* As = (seg == 1) ? Al : Ah;
        const u16* Ws = (seg == 2) ? WtL : WtH;
#pragma unroll 1
        for (int k0 = 0; k0 < 256; k0 += 64) {
            // stage A-tile [128][64] and W-tile [128][64]; linear LDS dest,
            // chunk-swizzled global source (rule: swizzle both sides or neither)
#pragma unroll
            for (int i = 0; i < 4; i++) {
                int t = i * 256 + tid;
                int row = t >> 3;
                int ch = (t & 7) ^ (row & 7);
                gload_lds16(As + (size_t)(m0 + row) * 256 + k0 + ch * 8,
                            (char*)lA + i * 4096 + wid * 1024);
            }
#pragma unroll
            for (int i = 0; i < 4; i++) {
                int t = i * 256 + tid;
                int row = t >> 3;
                int ch = (t & 7) ^ (row & 7);
                gload_lds16(Ws + (size_t)(n0 + row) * 256 + k0 + ch * 8,
                            (char*)lB + i * 4096 + wid * 1024);
            }
            __syncthreads();

#pragma unroll
            for (int kk = 0; kk < 2; kk++) {
                s16x8 af[4], bf[4];
#pragma unroll
                for (int mr = 0; mr < 4; mr++) {
                    int r = wm * 64 + mr * 16 + lr;
                    int q = (kk * 4 + lk) ^ (r & 7);
                    af[mr] = *(const s16x8*)&lA[r * 64 + q * 8];
                }
#pragma unroll
                for (int nr = 0; nr < 4; nr++) {
                    int r = wn * 64 + nr * 16 + lr;
                    int q = (kk * 4 + lk) ^ (r & 7);
                    bf[nr] = *(const s16x8*)&lB[r * 64 + q * 8];
                }
#pragma unroll
                for (int mr = 0; mr < 4; mr++)
#pragma unroll
                    for (int nr = 0; nr < 4; nr++)
                        acc[mr][nr] = __builtin_amdgcn_mfma_f32_16x16x32_bf16(
                            af[mr], bf[nr], acc[mr][nr], 0, 0, 0);
            }
            __syncthreads();
        }
    }

    // epilogue: C row = (lane>>4)*4 + j, col = lane&15 (m89-verified layout)
#pragma unroll
    for (int mr = 0; mr < 4; mr++) {
#pragma unroll
        for (int nr = 0; nr < 4; nr++) {
            int col = n0 + wn * 64 + nr * 16 + lr;
            float* Cp; const float* bp; int c;
            if (col < 256) { Cp = C0; bp = bias0; c = col; }
            else           { Cp = C1; bp = bias1; c = col - 256; }
            float b = bp[c];
#pragma unroll
            for (int j = 0; j < 4; j++) {
                int row = m0 + wm * 64 + mr * 16 + lk * 4 + j;
                if (row < M) Cp[(size_t)row * ldc + c] = acc[mr][nr][j] + b;
            }
        }
    }
}

// ---------------- CSR build ----------------
__global__ void count_deg(const int* __restrict__ dstA, int* __restrict__ deg) {
    int i = blockIdx.x * blockDim.x + threadIdx.x;
    int stride = gridDim.x * blockDim.x;
    for (; i < N_EDGES; i += stride) atomicAdd(&deg[dstA[i]], 1);
}

__global__ void scan_deg(const int* __restrict__ deg, int* __restrict__ rowstart,
                         int* __restrict__ cursor) {
    const int T = 1024;
    const int CHUNK = (N_NODES + T - 1) / T;
    __shared__ int part[T];
    int t = threadIdx.x;
    int lo = t * CHUNK;
    int hi = lo + CHUNK; if (hi > N_NODES) hi = N_NODES;
    int s = 0;
    for (int i = lo; i < hi; i++) s += deg[i];
    part[t] = s;
    __syncthreads();
    for (int off = 1; off < T; off <<= 1) {
        int v = 0;
        if (t >= off) v = part[t - off];
        __syncthreads();
        if (t >= off) part[t] += v;
        __syncthreads();
    }
    int run = (t == 0) ? 0 : part[t - 1];
    for (int i = lo; i < hi; i++) {
        rowstart[i] = run;
        cursor[i] = run;
        run += deg[i];
    }
    if (t == T - 1) rowstart[N_NODES] = part[T - 1];
}

__global__ void fill_csr(const int* __restrict__ srcA, const int* __restrict__ dstA,
                         int* __restrict__ cursor, int* __restrict__ csr_src) {
    int i = blockIdx.x * blockDim.x + threadIdx.x;
    int stride = gridDim.x * blockDim.x;
    for (; i < N_EDGES; i += stride) {
        int pos = atomicAdd(&cursor[dstA[i]], 1);
        csr_src[pos] = srcA[i];
    }
}

// ---------------- Fused GATv2 edge phase (one wave per destination) ----------------
__global__ void gat_fused(const float* __restrict__ xl, const float* __restrict__ xr,
                          const int* __restrict__ rowstart, const int* __restrict__ csr_src,
                          const float* __restrict__ att, float* __restrict__ out) {
    int wid = (blockIdx.x * blockDim.x + threadIdx.x) >> 6;
    int lane = threadIdx.x & 63;
    if (wid >= N_NODES) return;

    float xrv[4], attv[4], acc[4], den[4];
#pragma unroll
    for (int i = 0; i < 4; i++) {
        xrv[i] = xr[(size_t)wid * FDIM + i * 64 + lane];
        attv[i] = att[i * 64 + lane];
        acc[i] = 0.f;
        den[i] = 0.f;
    }

    int jb = rowstart[wid], je = rowstart[wid + 1];
    for (int j = jb; j < je; ++j) {
        int s = csr_src[j];
        const float* pl = xl + (size_t)s * FDIM;
        float xv[4], p[4];
#pragma unroll
        for (int i = 0; i < 4; i++) {
            xv[i] = pl[i * 64 + lane];
            float v = xv[i] + xrv[i];
            v = v > 0.f ? v : 0.2f * v;
            p[i] = v * attv[i];
        }
#pragma unroll
        for (int i = 0; i < 4; i++) {
            float q = p[i];
            q += __shfl_xor(q, 16);
            q += __shfl_xor(q, 8);
            q += __shfl_xor(q, 4);
            q += __shfl_xor(q, 2);
            q += __shfl_xor(q, 1);
            float ex = expf(q);
            den[i] += ex;
            acc[i] += ex * xv[i];
        }
    }
#pragma unroll
    for (int i = 0; i < 4; i++)
        out[(size_t)wid * FDIM + i * 64 + lane] = acc[i] / (den[i] + 1e-16f);
}

// ---------------- BatchNorm ----------------
__global__ void bn_stats(const float* __restrict__ X, float* __restrict__ sum,
                         float* __restrict__ sumsq, int nrows) {
    int col = threadIdx.x;
    float s = 0.f, ss = 0.f;
    for (int r = blockIdx.x; r < nrows; r += gridDim.x) {
        float v = X[(size_t)r * FDIM + col];
        s += v;
        ss += v * v;
    }
    atomicAdd(&sum[col], s);
    atomicAdd(&sumsq[col], ss);
}

__global__ void bn_finalize(const float* __restrict__ sum, const float* __restrict__ sumsq,
                            const float* __restrict__ gamma, const float* __restrict__ beta,
                            float* __restrict__ scale, float* __restrict__ shift) {
    int c = threadIdx.x;
    float mean = sum[c] * (1.f / N_NODES);
    float var = sumsq[c] * (1.f / N_NODES) - mean * mean;
    float sc = gamma[c] * rsqrtf(var + 1e-5f);
    scale[c] = sc;
    shift[c] = beta[c] - mean * sc;
}

// BN + ELU fused, output split to bf16 hi/lo (pad rows zeroed)
__global__ void bn_elu_split(const float* __restrict__ X, const float* __restrict__ scale,
                             const float* __restrict__ shift,
                             u16* __restrict__ hi, u16* __restrict__ lo) {
    int i = blockIdx.x * blockDim.x + threadIdx.x;   // float4 units
    int stride = gridDim.x * blockDim.x;
    const int n_valid4 = N_NODES * FDIM / 4;
    const int n_pad4 = NPAD * FDIM / 4;
    for (; i < n_pad4; i += stride) {
        u16 h[4], l[4];
        if (i < n_valid4) {
            f32x4 v = ((const f32x4*)X)[i];
            int c0 = (i * 4) & (FDIM - 1);
#pragma unroll
            for (int j = 0; j < 4; j++) {
                float f = v[j] * scale[c0 + j] + shift[c0 + j];
                f = f > 0.f ? f : expf(f) - 1.f;
                h[j] = f2bf(f);
                l[j] = f2bf(f - bf2f(h[j]));
            }
        } else {
#pragma unroll
            for (int j = 0; j < 4; j++) { h[j] = 0; l[j] = 0; }
        }
        ((ushort4*)hi)[i] = make_ushort4(h[0], h[1], h[2], h[3]);
        ((ushort4*)lo)[i] = make_ushort4(l[0], l[1], l[2], l[3]);
    }
}

// ---------------- Row L2 normalize ----------------
__global__ void l2norm(float* __restrict__ Y, int nrows) {
    int gtid = blockIdx.x * blockDim.x + threadIdx.x;
    int wave = gtid >> 6;
    int lane = threadIdx.x & 63;
    int nwaves = (gridDim.x * blockDim.x) >> 6;
    for (int r = wave; r < nrows; r += nwaves) {
        float v0 = Y[(size_t)r * OUTF + lane];
        float v1 = Y[(size_t)r * OUTF + 64 + lane];
        float ss = v0 * v0 + v1 * v1;
        ss += __shfl_xor(ss, 32);
        ss += __shfl_xor(ss, 16);
        ss += __shfl_xor(ss, 8);
        ss += __shfl_xor(ss, 4);
        ss += __shfl_xor(ss, 2);
        ss += __shfl_xor(ss, 1);
        float inv = 1.f / fmaxf(sqrtf(ss), 1e-12f);
        Y[(size_t)r * OUTF + lane] = v0 * inv;
        Y[(size_t)r * OUTF + 64 + lane] = v1 * inv;
    }
}

extern "C" void kernel_launch(void* const* d_in, const int* in_sizes, int n_in,
                              void* d_out, int out_size, void* d_ws, size_t ws_size,
                              hipStream_t stream) {
    const float* x     = (const float*)d_in[0];
    const int*   ei    = (const int*)d_in[1];
    const float* Wl1   = (const float*)d_in[2];
    const float* bl1   = (const float*)d_in[3];
    const float* Wr1   = (const float*)d_in[4];
    const float* br1   = (const float*)d_in[5];
    const float* att1  = (const float*)d_in[6];
    // d_in[7] = bias1 : cancels exactly inside batchnorm -> skipped
    const float* gamma1 = (const float*)d_in[8];
    const float* beta1  = (const float*)d_in[9];
    const float* Wl2   = (const float*)d_in[10];
    const float* bl2   = (const float*)d_in[11];
    const float* Wr2   = (const float*)d_in[12];
    const float* br2   = (const float*)d_in[13];
    const float* att2  = (const float*)d_in[14];
    // d_in[15] = bias2 : cancels inside batchnorm -> skipped
    const float* gamma2 = (const float*)d_in[16];
    const float* beta2  = (const float*)d_in[17];
    const float* Wfc   = (const float*)d_in[18];
    const float* bfc   = (const float*)d_in[19];

    const int* srcA = ei;
    const int* dstA = ei + N_EDGES;

    // Three rotating 102.5 MB regions + misc; total ~313 MB (under proven budget).
    const size_t REG = (size_t)NPAD * FDIM * 4;  // bytes; holds [N][256] f32 OR 2x bf16 [NPAD][256]
    char* p = (char*)d_ws;
    char* R0 = p;            p += REG;
    char* R1 = p;            p += REG;
    char* R2 = p;            p += REG;
    u16* WTH   = (u16*)p;              p += 512 * 256 * 2;
    u16* WTL   = (u16*)p;              p += 512 * 256 * 2;
    float* SUM = (float*)p;            p += FDIM * 4;
    float* SQ  = (float*)p;            p += FDIM * 4;
    float* SC  = (float*)p;            p += FDIM * 4;
    float* SH  = (float*)p;            p += FDIM * 4;
    int* DEG      = (int*)p;           p += (size_t)N_NODES * 4;
    int* ROWSTART = (int*)p;           p += (size_t)(N_NODES + 1) * 4;
    int* CURSOR   = (int*)p;           p += (size_t)N_NODES * 4;
    int* CSR      = (int*)p;           p += (size_t)N_EDGES * 4;

    const size_t HALF = (size_t)NPAD * FDIM;  // u16 elements per half-region

    const int gat_grid = (N_NODES + 3) / 4;
    const dim3 gemm_grid_layer(NPAD / 128, 4);
    const dim3 gemm_grid_fc(NPAD / 128, 1);

    // ---------------- CSR build ----------------
    hipMemsetAsync(DEG, 0, (size_t)N_NODES * sizeof(int), stream);
    count_deg<<<2048, 256, 0, stream>>>(dstA, DEG);
    scan_deg<<<1, 1024, 0, stream>>>(DEG, ROWSTART, CURSOR);
    fill_csr<<<2048, 256, 0, stream>>>(srcA, dstA, CURSOR, CSR);

    // ---------------- Layer 1 ----------------
    // AH/AL @ R0 ; gemm -> xl @ R1, xr @ R2 ; gat -> O @ R0
    split_hilo<<<4096, 256, 0, stream>>>(x, N_NODES * FDIM / 4, NPAD * FDIM / 4,
                                         (u16*)R0, (u16*)R0 + HALF);
    prep_w_layer<<<512, 256, 0, stream>>>(Wl1, Wr1, WTH, WTL);
    gemm3<<<gemm_grid_layer, 256, 0, stream>>>((u16*)R0, (u16*)R0 + HALF, WTH, WTL,
                                               bl1, br1, (float*)R1, (float*)R2, 256, N_NODES);
    gat_fused<<<gat_grid, 256, 0, stream>>>((float*)R1, (float*)R2, ROWSTART, CSR, att1, (float*)R0);

    hipMemsetAsync(SUM, 0, 2 * FDIM * sizeof(float), stream);
    bn_stats<<<1024, 256, 0, stream>>>((float*)R0, SUM, SQ, N_NODES);
    bn_finalize<<<1, 256, 0, stream>>>(SUM, SQ, gamma1, beta1, SC, SH);
    bn_elu_split<<<4096, 256, 0, stream>>>((float*)R0, SC, SH, (u16*)R1, (u16*)R1 + HALF);

    // ---------------- Layer 2 ----------------
    // AH/AL @ R1 ; gemm -> xl @ R2, xr @ R0 ; gat -> O @ R1
    prep_w_layer<<<512, 256, 0, stream>>>(Wl2, Wr2, WTH, WTL);
    gemm3<<<gemm_grid_layer, 256, 0, stream>>>((u16*)R1, (u16*)R1 + HALF, WTH, WTL,
                                               bl2, br2, (float*)R2, (float*)R0, 256, N_NODES);
    gat_fused<<<gat_grid, 256, 0, stream>>>((float*)R2, (float*)R0, ROWSTART, CSR, att2, (float*)R1);

    hipMemsetAsync(SUM, 0, 2 * FDIM * sizeof(float), stream);
    bn_stats<<<1024, 256, 0, stream>>>((float*)R1, SUM, SQ, N_NODES);
    bn_finalize<<<1, 256, 0, stream>>>(SUM, SQ, gamma2, beta2, SC, SH);
    bn_elu_split<<<4096, 256, 0, stream>>>((float*)R1, SC, SH, (u16*)R2, (u16*)R2 + HALF);

    // ---------------- FC + L2 normalize ----------------
    prep_w_fc<<<128, 256, 0, stream>>>(Wfc, WTH, WTL);
    gemm3<<<gemm_grid_fc, 256, 0, stream>>>((u16*)R2, (u16*)R2 + HALF, WTH, WTL,
                                            bfc, bfc, (float*)d_out, (float*)d_out, 128, N_NODES);
    l2norm<<<2048, 256, 0, stream>>>((float*)d_out, N_NODES);
}

// Round 5
// 1061.159 us; speedup vs baseline: 3.1048x; 1.2046x over previous
//
#include <hip/hip_runtime.h>
#include <math.h>

#define N_NODES 100000
#define N_EDGES 800000
#define NPAD    100096   // 782 * 128
#define FDIM 256
#define HEADS 8
#define CDIM 32
#define OUTF 128

#define SCAN_BLOCK 256
#define SCAN_NBLK ((N_NODES + SCAN_BLOCK - 1) / SCAN_BLOCK)   // 391

typedef short  s16x8 __attribute__((ext_vector_type(8)));
typedef float  f32x4 __attribute__((ext_vector_type(4)));
typedef unsigned short u16;

__device__ __forceinline__ u16 f2bf(float f) {
    unsigned u = __float_as_uint(f);
    unsigned r = (u + 0x7fff + ((u >> 16) & 1)) >> 16;
    return (u16)r;
}
__device__ __forceinline__ float bf2f(u16 h) {
    return __uint_as_float(((unsigned)h) << 16);
}

__device__ __forceinline__ void gload_lds16(const void* g, void* l) {
    __builtin_amdgcn_global_load_lds((const __attribute__((address_space(1))) void*)g,
                                     (__attribute__((address_space(3))) void*)l, 16, 0, 0);
}

// ---------------- split f32 -> bf16 hi/lo (pad region zeroed) ----------------
__global__ void split_hilo(const float* __restrict__ src, int n_valid4, int n_pad4,
                           u16* __restrict__ hi, u16* __restrict__ lo) {
    int i = blockIdx.x * blockDim.x + threadIdx.x;
    int stride = gridDim.x * blockDim.x;
    for (; i < n_pad4; i += stride) {
        f32x4 v = {0.f, 0.f, 0.f, 0.f};
        if (i < n_valid4) v = ((const f32x4*)src)[i];
        u16 h[4], l[4];
#pragma unroll
        for (int j = 0; j < 4; j++) {
            float f = v[j];
            h[j] = f2bf(f);
            l[j] = f2bf(f - bf2f(h[j]));
        }
        ((ushort4*)hi)[i] = make_ushort4(h[0], h[1], h[2], h[3]);
        ((ushort4*)lo)[i] = make_ushort4(l[0], l[1], l[2], l[3]);
    }
}

// ---------------- W prep: transpose + concat + split ----------------
__global__ void prep_w_layer(const float* __restrict__ Wl, const float* __restrict__ Wr,
                             u16* __restrict__ WtH, u16* __restrict__ WtL) {
    int idx = blockIdx.x * blockDim.x + threadIdx.x;
    if (idx >= 512 * 256) return;
    int n = idx >> 8, k = idx & 255;
    float w = (n < 256) ? Wl[k * 256 + n] : Wr[k * 256 + (n - 256)];
    u16 h = f2bf(w);
    WtH[idx] = h;
    WtL[idx] = f2bf(w - bf2f(h));
}

__global__ void prep_w_fc(const float* __restrict__ Wfc,
                          u16* __restrict__ WtH, u16* __restrict__ WtL) {
    int idx = blockIdx.x * blockDim.x + threadIdx.x;
    if (idx >= 128 * 256) return;
    int n = idx >> 8, k = idx & 255;
    float w = Wfc[k * 128 + n];
    u16 h = f2bf(w);
    WtH[idx] = h;
    WtL[idx] = f2bf(w - bf2f(h));
}

// ---------------- 3-term split-precision bf16 MFMA GEMM ----------------
__global__ __launch_bounds__(256) void gemm3(
        const u16* __restrict__ Ah, const u16* __restrict__ Al,
        const u16* __restrict__ WtH, const u16* __restrict__ WtL,
        const float* __restrict__ bias0, const float* __restrict__ bias1,
        float* __restrict__ C0, float* __restrict__ C1, int ldc, int M) {
    __shared__ __align__(16) u16 lA[128 * 64];
    __shared__ __align__(16) u16 lB[128 * 64];

    int tid = threadIdx.x;
    int wid = tid >> 6, lane = tid & 63;
    int wm = wid >> 1, wn = wid & 1;
    int m0 = blockIdx.x * 128, n0 = blockIdx.y * 128;
    int lr = lane & 15, lk = lane >> 4;

    f32x4 acc[4][4] = {};

#pragma unroll 1
    for (int seg = 0; seg < 3; seg++) {
        const u16* As = (seg == 1) ? Al : Ah;
        const u16* Ws = (seg == 2) ? WtL : WtH;
#pragma unroll 1
        for (int k0 = 0; k0 < 256; k0 += 64) {
#pragma unroll
            for (int i = 0; i < 4; i++) {
                int t = i * 256 + tid;
                int row = t >> 3;
                int ch = (t & 7) ^ (row & 7);
                gload_lds16(As + (size_t)(m0 + row) * 256 + k0 + ch * 8,
                            (char*)lA + i * 4096 + wid * 1024);
            }
#pragma unroll
            for (int i = 0; i < 4; i++) {
                int t = i * 256 + tid;
                int row = t >> 3;
                int ch = (t & 7) ^ (row & 7);
                gload_lds16(Ws + (size_t)(n0 + row) * 256 + k0 + ch * 8,
                            (char*)lB + i * 4096 + wid * 1024);
            }
            __syncthreads();

#pragma unroll
            for (int kk = 0; kk < 2; kk++) {
                s16x8 af[4], bf[4];
#pragma unroll
                for (int mr = 0; mr < 4; mr++) {
                    int r = wm * 64 + mr * 16 + lr;
                    int q = (kk * 4 + lk) ^ (r & 7);
                    af[mr] = *(const s16x8*)&lA[r * 64 + q * 8];
                }
#pragma unroll
                for (int nr = 0; nr < 4; nr++) {
                    int r = wn * 64 + nr * 16 + lr;
                    int q = (kk * 4 + lk) ^ (r & 7);
                    bf[nr] = *(const s16x8*)&lB[r * 64 + q * 8];
                }
#pragma unroll
                for (int mr = 0; mr < 4; mr++)
#pragma unroll
                    for (int nr = 0; nr < 4; nr++)
                        acc[mr][nr] = __builtin_amdgcn_mfma_f32_16x16x32_bf16(
                            af[mr], bf[nr], acc[mr][nr], 0, 0, 0);
            }
            __syncthreads();
        }
    }

#pragma unroll
    for (int mr = 0; mr < 4; mr++) {
#pragma unroll
        for (int nr = 0; nr < 4; nr++) {
            int col = n0 + wn * 64 + nr * 16 + lr;
            float* Cp; const float* bp; int c;
            if (col < 256) { Cp = C0; bp = bias0; c = col; }
            else           { Cp = C1; bp = bias1; c = col - 256; }
            float b = bp[c];
#pragma unroll
            for (int j = 0; j < 4; j++) {
                int row = m0 + wm * 64 + mr * 16 + lk * 4 + j;
                if (row < M) Cp[(size_t)row * ldc + c] = acc[mr][nr][j] + b;
            }
        }
    }
}

// ---------------- CSR build ----------------
__global__ void count_deg(const int* __restrict__ dstA, int* __restrict__ deg) {
    int i = blockIdx.x * blockDim.x + threadIdx.x;
    int stride = gridDim.x * blockDim.x;
    for (; i < N_EDGES; i += stride) atomicAdd(&deg[dstA[i]], 1);
}

// phase 1: per-block reduce of deg -> blocksum[SCAN_NBLK]
__global__ void scan_phase1(const int* __restrict__ deg, int* __restrict__ blocksum) {
    __shared__ int sdata[SCAN_BLOCK];
    int i = blockIdx.x * SCAN_BLOCK + threadIdx.x;
    sdata[threadIdx.x] = (i < N_NODES) ? deg[i] : 0;
    __syncthreads();
    for (int off = SCAN_BLOCK / 2; off > 0; off >>= 1) {
        if (threadIdx.x < off) sdata[threadIdx.x] += sdata[threadIdx.x + off];
        __syncthreads();
    }
    if (threadIdx.x == 0) blocksum[blockIdx.x] = sdata[0];
}

// phase 2: single small block scans blocksum in place (exclusive)
__global__ void scan_phase2(int* __restrict__ blocksum) {
    __shared__ int part[512];
    int t = threadIdx.x;
    int v = (t < SCAN_NBLK) ? blocksum[t] : 0;
    part[t] = v;
    __syncthreads();
    for (int off = 1; off < 512; off <<= 1) {
        int u = 0;
        if (t >= off) u = part[t - off];
        __syncthreads();
        if (t >= off) part[t] += u;
        __syncthreads();
    }
    if (t < SCAN_NBLK) blocksum[t] = part[t] - v;   // exclusive
}

// phase 3: per-block inclusive scan + block offset -> rowstart, cursor
__global__ void scan_phase3(const int* __restrict__ deg, const int* __restrict__ blockoff,
                            int* __restrict__ rowstart, int* __restrict__ cursor) {
    __shared__ int part[SCAN_BLOCK];
    int t = threadIdx.x;
    int i = blockIdx.x * SCAN_BLOCK + t;
    int v = (i < N_NODES) ? deg[i] : 0;
    part[t] = v;
    __syncthreads();
    for (int off = 1; off < SCAN_BLOCK; off <<= 1) {
        int u = 0;
        if (t >= off) u = part[t - off];
        __syncthreads();
        if (t >= off) part[t] += u;
        __syncthreads();
    }
    if (i < N_NODES) {
        int excl = blockoff[blockIdx.x] + part[t] - v;
        rowstart[i] = excl;
        cursor[i] = excl;
        if (i == N_NODES - 1) rowstart[N_NODES] = blockoff[blockIdx.x] + part[t];
    }
}

__global__ void fill_csr(const int* __restrict__ srcA, const int* __restrict__ dstA,
                         int* __restrict__ cursor, int* __restrict__ csr_src) {
    int i = blockIdx.x * blockDim.x + threadIdx.x;
    int stride = gridDim.x * blockDim.x;
    for (; i < N_EDGES; i += stride) {
        int pos = atomicAdd(&cursor[dstA[i]], 1);
        csr_src[pos] = srcA[i];
    }
}

// ---------------- Fused GATv2 edge phase (one wave per destination) ----------------
__global__ void gat_fused(const float* __restrict__ xl, const float* __restrict__ xr,
                          const int* __restrict__ rowstart, const int* __restrict__ csr_src,
                          const float* __restrict__ att, float* __restrict__ out) {
    int wid = (blockIdx.x * blockDim.x + threadIdx.x) >> 6;
    int lane = threadIdx.x & 63;
    if (wid >= N_NODES) return;

    float xrv[4], attv[4], acc[4], den[4];
#pragma unroll
    for (int i = 0; i < 4; i++) {
        xrv[i] = xr[(size_t)wid * FDIM + i * 64 + lane];
        attv[i] = att[i * 64 + lane];
        acc[i] = 0.f;
        den[i] = 0.f;
    }

    int jb = rowstart[wid], je = rowstart[wid + 1];
    for (int j = jb; j < je; ++j) {
        int s = csr_src[j];
        const float* pl = xl + (size_t)s * FDIM;
        float xv[4], p[4];
#pragma unroll
        for (int i = 0; i < 4; i++) {
            xv[i] = pl[i * 64 + lane];
            float v = xv[i] + xrv[i];
            v = v > 0.f ? v : 0.2f * v;
            p[i] = v * attv[i];
        }
#pragma unroll
        for (int i = 0; i < 4; i++) {
            float q = p[i];
            q += __shfl_xor(q, 16);
            q += __shfl_xor(q, 8);
            q += __shfl_xor(q, 4);
            q += __shfl_xor(q, 2);
            q += __shfl_xor(q, 1);
            float ex = expf(q);
            den[i] += ex;
            acc[i] += ex * xv[i];
        }
    }
#pragma unroll
    for (int i = 0; i < 4; i++)
        out[(size_t)wid * FDIM + i * 64 + lane] = acc[i] / (den[i] + 1e-16f);
}

// ---------------- BatchNorm ----------------
__global__ void bn_stats(const float* __restrict__ X, float* __restrict__ sum,
                         float* __restrict__ sumsq, int nrows) {
    int col = threadIdx.x;
    float s = 0.f, ss = 0.f;
    for (int r = blockIdx.x; r < nrows; r += gridDim.x) {
        float v = X[(size_t)r * FDIM + col];
        s += v;
        ss += v * v;
    }
    atomicAdd(&sum[col], s);
    atomicAdd(&sumsq[col], ss);
}

__global__ void bn_finalize(const float* __restrict__ sum, const float* __restrict__ sumsq,
                            const float* __restrict__ gamma, const float* __restrict__ beta,
                            float* __restrict__ scale, float* __restrict__ shift) {
    int c = threadIdx.x;
    float mean = sum[c] * (1.f / N_NODES);
    float var = sumsq[c] * (1.f / N_NODES) - mean * mean;
    float sc = gamma[c] * rsqrtf(var + 1e-5f);
    scale[c] = sc;
    shift[c] = beta[c] - mean * sc;
}

// BN + ELU fused, output split to bf16 hi/lo (pad rows zeroed)
__global__ void bn_elu_split(const float* __restrict__ X, const float* __restrict__ scale,
                             const float* __restrict__ shift,
                             u16* __restrict__ hi, u16* __restrict__ lo) {
    int i = blockIdx.x * blockDim.x + threadIdx.x;   // float4 units
    int stride = gridDim.x * blockDim.x;
    const int n_valid4 = N_NODES * FDIM / 4;
    const int n_pad4 = NPAD * FDIM / 4;
    for (; i < n_pad4; i += stride) {
        u16 h[4], l[4];
        if (i < n_valid4) {
            f32x4 v = ((const f32x4*)X)[i];
            int c0 = (i * 4) & (FDIM - 1);
#pragma unroll
            for (int j = 0; j < 4; j++) {
                float f = v[j] * scale[c0 + j] + shift[c0 + j];
                f = f > 0.f ? f : expf(f) - 1.f;
                h[j] = f2bf(f);
                l[j] = f2bf(f - bf2f(h[j]));
            }
        } else {
#pragma unroll
            for (int j = 0; j < 4; j++) { h[j] = 0; l[j] = 0; }
        }
        ((ushort4*)hi)[i] = make_ushort4(h[0], h[1], h[2], h[3]);
        ((ushort4*)lo)[i] = make_ushort4(l[0], l[1], l[2], l[3]);
    }
}

// ---------------- Row L2 normalize ----------------
__global__ void l2norm(float* __restrict__ Y, int nrows) {
    int gtid = blockIdx.x * blockDim.x + threadIdx.x;
    int wave = gtid >> 6;
    int lane = threadIdx.x & 63;
    int nwaves = (gridDim.x * blockDim.x) >> 6;
    for (int r = wave; r < nrows; r += nwaves) {
        float v0 = Y[(size_t)r * OUTF + lane];
        float v1 = Y[(size_t)r * OUTF + 64 + lane];
        float ss = v0 * v0 + v1 * v1;
        ss += __shfl_xor(ss, 32);
        ss += __shfl_xor(ss, 16);
        ss += __shfl_xor(ss, 8);
        ss += __shfl_xor(ss, 4);
        ss += __shfl_xor(ss, 2);
        ss += __shfl_xor(ss, 1);
        float inv = 1.f / fmaxf(sqrtf(ss), 1e-12f);
        Y[(size_t)r * OUTF + lane] = v0 * inv;
        Y[(size_t)r * OUTF + 64 + lane] = v1 * inv;
    }
}

extern "C" void kernel_launch(void* const* d_in, const int* in_sizes, int n_in,
                              void* d_out, int out_size, void* d_ws, size_t ws_size,
                              hipStream_t stream) {
    const float* x     = (const float*)d_in[0];
    const int*   ei    = (const int*)d_in[1];
    const float* Wl1   = (const float*)d_in[2];
    const float* bl1   = (const float*)d_in[3];
    const float* Wr1   = (const float*)d_in[4];
    const float* br1   = (const float*)d_in[5];
    const float* att1  = (const float*)d_in[6];
    // d_in[7] = bias1 : cancels exactly inside batchnorm -> skipped
    const float* gamma1 = (const float*)d_in[8];
    const float* beta1  = (const float*)d_in[9];
    const float* Wl2   = (const float*)d_in[10];
    const float* bl2   = (const float*)d_in[11];
    const float* Wr2   = (const float*)d_in[12];
    const float* br2   = (const float*)d_in[13];
    const float* att2  = (const float*)d_in[14];
    // d_in[15] = bias2 : cancels inside batchnorm -> skipped
    const float* gamma2 = (const float*)d_in[16];
    const float* beta2  = (const float*)d_in[17];
    const float* Wfc   = (const float*)d_in[18];
    const float* bfc   = (const float*)d_in[19];

    const int* srcA = ei;
    const int* dstA = ei + N_EDGES;

    // Three rotating 102.5 MB regions + misc; total ~313 MB (under proven budget).
    const size_t REG = (size_t)NPAD * FDIM * 4;
    char* p = (char*)d_ws;
    char* R0 = p;            p += REG;
    char* R1 = p;            p += REG;
    char* R2 = p;            p += REG;
    u16* WTH   = (u16*)p;              p += 512 * 256 * 2;
    u16* WTL   = (u16*)p;              p += 512 * 256 * 2;
    float* SUM = (float*)p;            p += FDIM * 4;
    float* SQ  = (float*)p;            p += FDIM * 4;
    float* SC  = (float*)p;            p += FDIM * 4;
    float* SH  = (float*)p;            p += FDIM * 4;
    int* DEG      = (int*)p;           p += (size_t)N_NODES * 4;
    int* ROWSTART = (int*)p;           p += (size_t)(N_NODES + 1) * 4;
    int* CURSOR   = (int*)p;           p += (size_t)N_NODES * 4;
    int* CSR      = (int*)p;           p += (size_t)N_EDGES * 4;
    int* BLKSUM   = (int*)p;           p += (size_t)SCAN_NBLK * 4;

    const size_t HALF = (size_t)NPAD * FDIM;  // u16 elements per half-region

    const int gat_grid = (N_NODES + 3) / 4;
    const dim3 gemm_grid_layer(NPAD / 128, 4);
    const dim3 gemm_grid_fc(NPAD / 128, 1);

    // ---------------- CSR build ----------------
    hipMemsetAsync(DEG, 0, (size_t)N_NODES * sizeof(int), stream);
    count_deg<<<2048, 256, 0, stream>>>(dstA, DEG);
    scan_phase1<<<SCAN_NBLK, SCAN_BLOCK, 0, stream>>>(DEG, BLKSUM);
    scan_phase2<<<1, 512, 0, stream>>>(BLKSUM);
    scan_phase3<<<SCAN_NBLK, SCAN_BLOCK, 0, stream>>>(DEG, BLKSUM, ROWSTART, CURSOR);
    fill_csr<<<2048, 256, 0, stream>>>(srcA, dstA, CURSOR, CSR);

    // ---------------- Layer 1 ----------------
    split_hilo<<<4096, 256, 0, stream>>>(x, N_NODES * FDIM / 4, NPAD * FDIM / 4,
                                         (u16*)R0, (u16*)R0 + HALF);
    prep_w_layer<<<512, 256, 0, stream>>>(Wl1, Wr1, WTH, WTL);
    gemm3<<<gemm_grid_layer, 256, 0, stream>>>((u16*)R0, (u16*)R0 + HALF, WTH, WTL,
                                               bl1, br1, (float*)R1, (float*)R2, 256, N_NODES);
    gat_fused<<<gat_grid, 256, 0, stream>>>((float*)R1, (float*)R2, ROWSTART, CSR, att1, (float*)R0);

    hipMemsetAsync(SUM, 0, 2 * FDIM * sizeof(float), stream);
    bn_stats<<<1024, 256, 0, stream>>>((float*)R0, SUM, SQ, N_NODES);
    bn_finalize<<<1, 256, 0, stream>>>(SUM, SQ, gamma1, beta1, SC, SH);
    bn_elu_split<<<4096, 256, 0, stream>>>((float*)R0, SC, SH, (u16*)R1, (u16*)R1 + HALF);

    // ---------------- Layer 2 ----------------
    prep_w_layer<<<512, 256, 0, stream>>>(Wl2, Wr2, WTH, WTL);
    gemm3<<<gemm_grid_layer, 256, 0, stream>>>((u16*)R1, (u16*)R1 + HALF, WTH, WTL,
                                               bl2, br2, (float*)R2, (float*)R0, 256, N_NODES);
    gat_fused<<<gat_grid, 256, 0, stream>>>((float*)R2, (float*)R0, ROWSTART, CSR, att2, (float*)R1);

    hipMemsetAsync(SUM, 0, 2 * FDIM * sizeof(float), stream);
    bn_stats<<<1024, 256, 0, stream>>>((float*)R1, SUM, SQ, N_NODES);
    bn_finalize<<<1, 256, 0, stream>>>(SUM, SQ, gamma2, beta2, SC, SH);
    bn_elu_split<<<4096, 256, 0, stream>>>((float*)R1, SC, SH, (u16*)R2, (u16*)R2 + HALF);

    // ---------------- FC + L2 normalize ----------------
    prep_w_fc<<<128, 256, 0, stream>>>(Wfc, WTH, WTL);
    gemm3<<<gemm_grid_fc, 256, 0, stream>>>((u16*)R2, (u16*)R2 + HALF, WTH, WTL,
                                            bfc, bfc, (float*)d_out, (float*)d_out, 128, N_NODES);
    l2norm<<<2048, 256, 0, stream>>>((float*)d_out, N_NODES);
}

// Round 6
// 972.469 us; speedup vs baseline: 3.3879x; 1.0912x over previous
//
#include <hip/hip_runtime.h>
#include <math.h>

#define N_NODES 100000
#define N_EDGES 800000
#define NPAD    100096   // 782 * 128
#define FDIM 256
#define HEADS 8
#define CDIM 32
#define OUTF 128

#define SCAN_BLOCK 256
#define SCAN_NBLK ((N_NODES + SCAN_BLOCK - 1) / SCAN_BLOCK)   // 391

typedef short  s16x8 __attribute__((ext_vector_type(8)));
typedef float  f32x4 __attribute__((ext_vector_type(4)));
typedef unsigned short u16;

__device__ __forceinline__ u16 f2bf(float f) {
    unsigned u = __float_as_uint(f);
    unsigned r = (u + 0x7fff + ((u >> 16) & 1)) >> 16;
    return (u16)r;
}
__device__ __forceinline__ float bf2f(u16 h) {
    return __uint_as_float(((unsigned)h) << 16);
}

__device__ __forceinline__ void gload_lds16(const void* g, void* l) {
    __builtin_amdgcn_global_load_lds((const __attribute__((address_space(1))) void*)g,
                                     (__attribute__((address_space(3))) void*)l, 16, 0, 0);
}

// ---------------- split f32 -> bf16 hi/lo (pad region zeroed) ----------------
__global__ void split_hilo(const float* __restrict__ src, int n_valid4, int n_pad4,
                           u16* __restrict__ hi, u16* __restrict__ lo) {
    int i = blockIdx.x * blockDim.x + threadIdx.x;
    int stride = gridDim.x * blockDim.x;
    for (; i < n_pad4; i += stride) {
        f32x4 v = {0.f, 0.f, 0.f, 0.f};
        if (i < n_valid4) v = ((const f32x4*)src)[i];
        u16 h[4], l[4];
#pragma unroll
        for (int j = 0; j < 4; j++) {
            float f = v[j];
            h[j] = f2bf(f);
            l[j] = f2bf(f - bf2f(h[j]));
        }
        ((ushort4*)hi)[i] = make_ushort4(h[0], h[1], h[2], h[3]);
        ((ushort4*)lo)[i] = make_ushort4(l[0], l[1], l[2], l[3]);
    }
}

// ---------------- W prep: transpose + concat + split ----------------
__global__ void prep_w_layer(const float* __restrict__ Wl, const float* __restrict__ Wr,
                             u16* __restrict__ WtH, u16* __restrict__ WtL) {
    int idx = blockIdx.x * blockDim.x + threadIdx.x;
    if (idx >= 512 * 256) return;
    int n = idx >> 8, k = idx & 255;
    float w = (n < 256) ? Wl[k * 256 + n] : Wr[k * 256 + (n - 256)];
    u16 h = f2bf(w);
    WtH[idx] = h;
    WtL[idx] = f2bf(w - bf2f(h));
}

__global__ void prep_w_fc(const float* __restrict__ Wfc,
                          u16* __restrict__ WtH, u16* __restrict__ WtL) {
    int idx = blockIdx.x * blockDim.x + threadIdx.x;
    if (idx >= 128 * 256) return;
    int n = idx >> 8, k = idx & 255;
    float w = Wfc[k * 128 + n];
    u16 h = f2bf(w);
    WtH[idx] = h;
    WtL[idx] = f2bf(w - bf2f(h));
}

// ---------------- 3-term split-precision bf16 MFMA GEMM ----------------
__global__ __launch_bounds__(256) void gemm3(
        const u16* __restrict__ Ah, const u16* __restrict__ Al,
        const u16* __restrict__ WtH, const u16* __restrict__ WtL,
        const float* __restrict__ bias0, const float* __restrict__ bias1,
        float* __restrict__ C0, float* __restrict__ C1, int ldc, int M) {
    __shared__ __align__(16) u16 lA[128 * 64];
    __shared__ __align__(16) u16 lB[128 * 64];

    int tid = threadIdx.x;
    int wid = tid >> 6, lane = tid & 63;
    int wm = wid >> 1, wn = wid & 1;
    int m0 = blockIdx.x * 128, n0 = blockIdx.y * 128;
    int lr = lane & 15, lk = lane >> 4;

    f32x4 acc[4][4] = {};

#pragma unroll 1
    for (int seg = 0; seg < 3; seg++) {
        const u16* As = (seg == 1) ? Al : Ah;
        const u16* Ws = (seg == 2) ? WtL : WtH;
#pragma unroll 1
        for (int k0 = 0; k0 < 256; k0 += 64) {
#pragma unroll
            for (int i = 0; i < 4; i++) {
                int t = i * 256 + tid;
                int row = t >> 3;
                int ch = (t & 7) ^ (row & 7);
                gload_lds16(As + (size_t)(m0 + row) * 256 + k0 + ch * 8,
                            (char*)lA + i * 4096 + wid * 1024);
            }
#pragma unroll
            for (int i = 0; i < 4; i++) {
                int t = i * 256 + tid;
                int row = t >> 3;
                int ch = (t & 7) ^ (row & 7);
                gload_lds16(Ws + (size_t)(n0 + row) * 256 + k0 + ch * 8,
                            (char*)lB + i * 4096 + wid * 1024);
            }
            __syncthreads();

#pragma unroll
            for (int kk = 0; kk < 2; kk++) {
                s16x8 af[4], bf[4];
#pragma unroll
                for (int mr = 0; mr < 4; mr++) {
                    int r = wm * 64 + mr * 16 + lr;
                    int q = (kk * 4 + lk) ^ (r & 7);
                    af[mr] = *(const s16x8*)&lA[r * 64 + q * 8];
                }
#pragma unroll
                for (int nr = 0; nr < 4; nr++) {
                    int r = wn * 64 + nr * 16 + lr;
                    int q = (kk * 4 + lk) ^ (r & 7);
                    bf[nr] = *(const s16x8*)&lB[r * 64 + q * 8];
                }
#pragma unroll
                for (int mr = 0; mr < 4; mr++)
#pragma unroll
                    for (int nr = 0; nr < 4; nr++)
                        acc[mr][nr] = __builtin_amdgcn_mfma_f32_16x16x32_bf16(
                            af[mr], bf[nr], acc[mr][nr], 0, 0, 0);
            }
            __syncthreads();
        }
    }

#pragma unroll
    for (int mr = 0; mr < 4; mr++) {
#pragma unroll
        for (int nr = 0; nr < 4; nr++) {
            int col = n0 + wn * 64 + nr * 16 + lr;
            float* Cp; const float* bp; int c;
            if (col < 256) { Cp = C0; bp = bias0; c = col; }
            else           { Cp = C1; bp = bias1; c = col - 256; }
            float b = bp[c];
#pragma unroll
            for (int j = 0; j < 4; j++) {
                int row = m0 + wm * 64 + mr * 16 + lk * 4 + j;
                if (row < M) Cp[(size_t)row * ldc + c] = acc[mr][nr][j] + b;
            }
        }
    }
}

// ---------------- CSR build ----------------
__global__ void count_deg(const int* __restrict__ dstA, int* __restrict__ deg) {
    int i = blockIdx.x * blockDim.x + threadIdx.x;
    int stride = gridDim.x * blockDim.x;
    for (; i < N_EDGES; i += stride) atomicAdd(&deg[dstA[i]], 1);
}

__global__ void scan_phase1(const int* __restrict__ deg, int* __restrict__ blocksum) {
    __shared__ int sdata[SCAN_BLOCK];
    int i = blockIdx.x * SCAN_BLOCK + threadIdx.x;
    sdata[threadIdx.x] = (i < N_NODES) ? deg[i] : 0;
    __syncthreads();
    for (int off = SCAN_BLOCK / 2; off > 0; off >>= 1) {
        if (threadIdx.x < off) sdata[threadIdx.x] += sdata[threadIdx.x + off];
        __syncthreads();
    }
    if (threadIdx.x == 0) blocksum[blockIdx.x] = sdata[0];
}

__global__ void scan_phase2(int* __restrict__ blocksum) {
    __shared__ int part[512];
    int t = threadIdx.x;
    int v = (t < SCAN_NBLK) ? blocksum[t] : 0;
    part[t] = v;
    __syncthreads();
    for (int off = 1; off < 512; off <<= 1) {
        int u = 0;
        if (t >= off) u = part[t - off];
        __syncthreads();
        if (t >= off) part[t] += u;
        __syncthreads();
    }
    if (t < SCAN_NBLK) blocksum[t] = part[t] - v;   // exclusive
}

__global__ void scan_phase3(const int* __restrict__ deg, const int* __restrict__ blockoff,
                            int* __restrict__ rowstart, int* __restrict__ cursor) {
    __shared__ int part[SCAN_BLOCK];
    int t = threadIdx.x;
    int i = blockIdx.x * SCAN_BLOCK + t;
    int v = (i < N_NODES) ? deg[i] : 0;
    part[t] = v;
    __syncthreads();
    for (int off = 1; off < SCAN_BLOCK; off <<= 1) {
        int u = 0;
        if (t >= off) u = part[t - off];
        __syncthreads();
        if (t >= off) part[t] += u;
        __syncthreads();
    }
    if (i < N_NODES) {
        int excl = blockoff[blockIdx.x] + part[t] - v;
        rowstart[i] = excl;
        cursor[i] = excl;
        if (i == N_NODES - 1) rowstart[N_NODES] = blockoff[blockIdx.x] + part[t];
    }
}

__global__ void fill_csr(const int* __restrict__ srcA, const int* __restrict__ dstA,
                         int* __restrict__ cursor, int* __restrict__ csr_src) {
    int i = blockIdx.x * blockDim.x + threadIdx.x;
    int stride = gridDim.x * blockDim.x;
    for (; i < N_EDGES; i += stride) {
        int pos = atomicAdd(&cursor[dstA[i]], 1);
        csr_src[pos] = srcA[i];
    }
}

// ---------------- Fused GATv2 edge phase (one wave per destination) ----------------
// Multi-value folded butterfly reduce: 9 shfl instead of 20, 1 expf instead of 4.
__global__ void gat_fused(const float* __restrict__ xl, const float* __restrict__ xr,
                          const int* __restrict__ rowstart, const int* __restrict__ csr_src,
                          const float* __restrict__ att, float* __restrict__ out) {
    int wid = (blockIdx.x * blockDim.x + threadIdx.x) >> 6;
    int lane = threadIdx.x & 63;
    if (wid >= N_NODES) return;

    float xrv[4], attv[4], acc[4], den[4];
#pragma unroll
    for (int i = 0; i < 4; i++) {
        xrv[i] = xr[(size_t)wid * FDIM + i * 64 + lane];
        attv[i] = att[i * 64 + lane];
        acc[i] = 0.f;
        den[i] = 0.f;
    }

    int jb = rowstart[wid], je = rowstart[wid + 1];
    if (jb < je) {
        // prefetch first edge's row
        float xv[4];
        {
            const float* pl = xl + (size_t)csr_src[jb] * FDIM;
#pragma unroll
            for (int i = 0; i < 4; i++) xv[i] = pl[i * 64 + lane];
        }
        int hb = lane & 32;  // half base for broadcast lane computation

        for (int j = jb; j < je; ++j) {
            // prefetch next edge's row (last iter: re-load current, L1-hot, unused cost)
            int j2 = (j + 1 < je) ? j + 1 : j;
            float nxt[4];
            {
                const float* p2 = xl + (size_t)csr_src[j2] * FDIM;
#pragma unroll
                for (int i = 0; i < 4; i++) nxt[i] = p2[i * 64 + lane];
            }

            float p[4];
#pragma unroll
            for (int i = 0; i < 4; i++) {
                float v = xv[i] + xrv[i];
                v = v > 0.f ? v : 0.2f * v;
                p[i] = v * attv[i];
            }
            // folded 4-value butterfly over the 32-lane half (offsets 16..1)
#pragma unroll
            for (int i = 0; i < 4; i++) p[i] += __shfl_xor(p[i], 16);
            float a = (lane & 16) ? p[1] : p[0];
            float b = (lane & 16) ? p[3] : p[2];
            a += __shfl_xor(a, 8);
            b += __shfl_xor(b, 8);
            float c = (lane & 8) ? b : a;
            c += __shfl_xor(c, 4);
            c += __shfl_xor(c, 2);
            c += __shfl_xor(c, 1);
            // lane holds S_i with i = bit4(lane) + 2*bit3(lane)
            float e = __expf(c);
            // broadcast each head-sum's exp back to all lanes of the half
#pragma unroll
            for (int i = 0; i < 4; i++) {
                float ex = __shfl(e, hb | ((i & 1) << 4) | ((i >> 1) << 3));
                den[i] += ex;
                acc[i] += ex * xv[i];
            }
#pragma unroll
            for (int i = 0; i < 4; i++) xv[i] = nxt[i];
        }
    }
#pragma unroll
    for (int i = 0; i < 4; i++)
        out[(size_t)wid * FDIM + i * 64 + lane] = acc[i] / (den[i] + 1e-16f);
}

// ---------------- BatchNorm ----------------
__global__ void bn_stats(const float* __restrict__ X, float* __restrict__ sum,
                         float* __restrict__ sumsq, int nrows) {
    int col = threadIdx.x;
    float s = 0.f, ss = 0.f;
    for (int r = blockIdx.x; r < nrows; r += gridDim.x) {
        float v = X[(size_t)r * FDIM + col];
        s += v;
        ss += v * v;
    }
    atomicAdd(&sum[col], s);
    atomicAdd(&sumsq[col], ss);
}

__global__ void bn_finalize(const float* __restrict__ sum, const float* __restrict__ sumsq,
                            const float* __restrict__ gamma, const float* __restrict__ beta,
                            float* __restrict__ scale, float* __restrict__ shift) {
    int c = threadIdx.x;
    float mean = sum[c] * (1.f / N_NODES);
    float var = sumsq[c] * (1.f / N_NODES) - mean * mean;
    float sc = gamma[c] * rsqrtf(var + 1e-5f);
    scale[c] = sc;
    shift[c] = beta[c] - mean * sc;
}

// BN + ELU fused, output split to bf16 hi/lo (pad rows zeroed)
__global__ void bn_elu_split(const float* __restrict__ X, const float* __restrict__ scale,
                             const float* __restrict__ shift,
                             u16* __restrict__ hi, u16* __restrict__ lo) {
    int i = blockIdx.x * blockDim.x + threadIdx.x;   // float4 units
    int stride = gridDim.x * blockDim.x;
    const int n_valid4 = N_NODES * FDIM / 4;
    const int n_pad4 = NPAD * FDIM / 4;
    for (; i < n_pad4; i += stride) {
        u16 h[4], l[4];
        if (i < n_valid4) {
            f32x4 v = ((const f32x4*)X)[i];
            int c0 = (i * 4) & (FDIM - 1);
#pragma unroll
            for (int j = 0; j < 4; j++) {
                float f = v[j] * scale[c0 + j] + shift[c0 + j];
                f = f > 0.f ? f : expf(f) - 1.f;
                h[j] = f2bf(f);
                l[j] = f2bf(f - bf2f(h[j]));
            }
        } else {
#pragma unroll
            for (int j = 0; j < 4; j++) { h[j] = 0; l[j] = 0; }
        }
        ((ushort4*)hi)[i] = make_ushort4(h[0], h[1], h[2], h[3]);
        ((ushort4*)lo)[i] = make_ushort4(l[0], l[1], l[2], l[3]);
    }
}

// ---------------- Row L2 normalize ----------------
__global__ void l2norm(float* __restrict__ Y, int nrows) {
    int gtid = blockIdx.x * blockDim.x + threadIdx.x;
    int wave = gtid >> 6;
    int lane = threadIdx.x & 63;
    int nwaves = (gridDim.x * blockDim.x) >> 6;
    for (int r = wave; r < nrows; r += nwaves) {
        float v0 = Y[(size_t)r * OUTF + lane];
        float v1 = Y[(size_t)r * OUTF + 64 + lane];
        float ss = v0 * v0 + v1 * v1;
        ss += __shfl_xor(ss, 32);
        ss += __shfl_xor(ss, 16);
        ss += __shfl_xor(ss, 8);
        ss += __shfl_xor(ss, 4);
        ss += __shfl_xor(ss, 2);
        ss += __shfl_xor(ss, 1);
        float inv = 1.f / fmaxf(sqrtf(ss), 1e-12f);
        Y[(size_t)r * OUTF + lane] = v0 * inv;
        Y[(size_t)r * OUTF + 64 + lane] = v1 * inv;
    }
}

extern "C" void kernel_launch(void* const* d_in, const int* in_sizes, int n_in,
                              void* d_out, int out_size, void* d_ws, size_t ws_size,
                              hipStream_t stream) {
    const float* x     = (const float*)d_in[0];
    const int*   ei    = (const int*)d_in[1];
    const float* Wl1   = (const float*)d_in[2];
    const float* bl1   = (const float*)d_in[3];
    const float* Wr1   = (const float*)d_in[4];
    const float* br1   = (const float*)d_in[5];
    const float* att1  = (const float*)d_in[6];
    // d_in[7] = bias1 : cancels exactly inside batchnorm -> skipped
    const float* gamma1 = (const float*)d_in[8];
    const float* beta1  = (const float*)d_in[9];
    const float* Wl2   = (const float*)d_in[10];
    const float* bl2   = (const float*)d_in[11];
    const float* Wr2   = (const float*)d_in[12];
    const float* br2   = (const float*)d_in[13];
    const float* att2  = (const float*)d_in[14];
    // d_in[15] = bias2 : cancels inside batchnorm -> skipped
    const float* gamma2 = (const float*)d_in[16];
    const float* beta2  = (const float*)d_in[17];
    const float* Wfc   = (const float*)d_in[18];
    const float* bfc   = (const float*)d_in[19];

    const int* srcA = ei;
    const int* dstA = ei + N_EDGES;

    const size_t REG = (size_t)NPAD * FDIM * 4;
    char* p = (char*)d_ws;
    char* R0 = p;            p += REG;
    char* R1 = p;            p += REG;
    char* R2 = p;            p += REG;
    u16* WTH   = (u16*)p;              p += 512 * 256 * 2;
    u16* WTL   = (u16*)p;              p += 512 * 256 * 2;
    float* SUM = (float*)p;            p += FDIM * 4;
    float* SQ  = (float*)p;            p += FDIM * 4;
    float* SC  = (float*)p;            p += FDIM * 4;
    float* SH  = (float*)p;            p += FDIM * 4;
    int* DEG      = (int*)p;           p += (size_t)N_NODES * 4;
    int* ROWSTART = (int*)p;           p += (size_t)(N_NODES + 1) * 4;
    int* CURSOR   = (int*)p;           p += (size_t)N_NODES * 4;
    int* CSR      = (int*)p;           p += (size_t)N_EDGES * 4;
    int* BLKSUM   = (int*)p;           p += (size_t)SCAN_NBLK * 4;

    const size_t HALF = (size_t)NPAD * FDIM;  // u16 elements per half-region

    const int gat_grid = (N_NODES + 3) / 4;
    const dim3 gemm_grid_layer(NPAD / 128, 4);
    const dim3 gemm_grid_fc(NPAD / 128, 1);

    // ---------------- CSR build ----------------
    hipMemsetAsync(DEG, 0, (size_t)N_NODES * sizeof(int), stream);
    count_deg<<<2048, 256, 0, stream>>>(dstA, DEG);
    scan_phase1<<<SCAN_NBLK, SCAN_BLOCK, 0, stream>>>(DEG, BLKSUM);
    scan_phase2<<<1, 512, 0, stream>>>(BLKSUM);
    scan_phase3<<<SCAN_NBLK, SCAN_BLOCK, 0, stream>>>(DEG, BLKSUM, ROWSTART, CURSOR);
    fill_csr<<<2048, 256, 0, stream>>>(srcA, dstA, CURSOR, CSR);

    // ---------------- Layer 1 ----------------
    split_hilo<<<4096, 256, 0, stream>>>(x, N_NODES * FDIM / 4, NPAD * FDIM / 4,
                                         (u16*)R0, (u16*)R0 + HALF);
    prep_w_layer<<<512, 256, 0, stream>>>(Wl1, Wr1, WTH, WTL);
    gemm3<<<gemm_grid_layer, 256, 0, stream>>>((u16*)R0, (u16*)R0 + HALF, WTH, WTL,
                                               bl1, br1, (float*)R1, (float*)R2, 256, N_NODES);
    gat_fused<<<gat_grid, 256, 0, stream>>>((float*)R1, (float*)R2, ROWSTART, CSR, att1, (float*)R0);

    hipMemsetAsync(SUM, 0, 2 * FDIM * sizeof(float), stream);
    bn_stats<<<1024, 256, 0, stream>>>((float*)R0, SUM, SQ, N_NODES);
    bn_finalize<<<1, 256, 0, stream>>>(SUM, SQ, gamma1, beta1, SC, SH);
    bn_elu_split<<<4096, 256, 0, stream>>>((float*)R0, SC, SH, (u16*)R1, (u16*)R1 + HALF);

    // ---------------- Layer 2 ----------------
    prep_w_layer<<<512, 256, 0, stream>>>(Wl2, Wr2, WTH, WTL);
    gemm3<<<gemm_grid_layer, 256, 0, stream>>>((u16*)R1, (u16*)R1 + HALF, WTH, WTL,
                                               bl2, br2, (float*)R2, (float*)R0, 256, N_NODES);
    gat_fused<<<gat_grid, 256, 0, stream>>>((float*)R2, (float*)R0, ROWSTART, CSR, att2, (float*)R1);

    hipMemsetAsync(SUM, 0, 2 * FDIM * sizeof(float), stream);
    bn_stats<<<1024, 256, 0, stream>>>((float*)R1, SUM, SQ, N_NODES);
    bn_finalize<<<1, 256, 0, stream>>>(SUM, SQ, gamma2, beta2, SC, SH);
    bn_elu_split<<<4096, 256, 0, stream>>>((float*)R1, SC, SH, (u16*)R2, (u16*)R2 + HALF);

    // ---------------- FC + L2 normalize ----------------
    prep_w_fc<<<128, 256, 0, stream>>>(Wfc, WTH, WTL);
    gemm3<<<gemm_grid_fc, 256, 0, stream>>>((u16*)R2, (u16*)R2 + HALF, WTH, WTL,
                                            bfc, bfc, (float*)d_out, (float*)d_out, 128, N_NODES);
    l2norm<<<2048, 256, 0, stream>>>((float*)d_out, N_NODES);
}

// Round 7
// 955.237 us; speedup vs baseline: 3.4490x; 1.0180x over previous
//
#include <hip/hip_runtime.h>
#include <math.h>

#define N_NODES 100000
#define N_EDGES 800000
#define NPAD    100096   // 782 * 128
#define FDIM 256
#define HEADS 8
#define CDIM 32
#define OUTF 128

#define SCAN_BLOCK 256
#define SCAN_NBLK ((N_NODES + SCAN_BLOCK - 1) / SCAN_BLOCK)   // 391

typedef short  s16x8 __attribute__((ext_vector_type(8)));
typedef float  f32x4 __attribute__((ext_vector_type(4)));
typedef unsigned short u16;

__device__ __forceinline__ u16 f2bf(float f) {
    unsigned u = __float_as_uint(f);
    unsigned r = (u + 0x7fff + ((u >> 16) & 1)) >> 16;
    return (u16)r;
}
__device__ __forceinline__ float bf2f(u16 h) {
    return __uint_as_float(((unsigned)h) << 16);
}

__device__ __forceinline__ void gload_lds16(const void* g, void* l) {
    __builtin_amdgcn_global_load_lds((const __attribute__((address_space(1))) void*)g,
                                     (__attribute__((address_space(3))) void*)l, 16, 0, 0);
}

// ---------------- split f32 -> bf16 hi/lo (pad region zeroed) ----------------
__global__ void split_hilo(const float* __restrict__ src, int n_valid4, int n_pad4,
                           u16* __restrict__ hi, u16* __restrict__ lo) {
    int i = blockIdx.x * blockDim.x + threadIdx.x;
    int stride = gridDim.x * blockDim.x;
    for (; i < n_pad4; i += stride) {
        f32x4 v = {0.f, 0.f, 0.f, 0.f};
        if (i < n_valid4) v = ((const f32x4*)src)[i];
        u16 h[4], l[4];
#pragma unroll
        for (int j = 0; j < 4; j++) {
            float f = v[j];
            h[j] = f2bf(f);
            l[j] = f2bf(f - bf2f(h[j]));
        }
        ((ushort4*)hi)[i] = make_ushort4(h[0], h[1], h[2], h[3]);
        ((ushort4*)lo)[i] = make_ushort4(l[0], l[1], l[2], l[3]);
    }
}

// ---------------- W prep: transpose + concat + split ----------------
__global__ void prep_w_layer(const float* __restrict__ Wl, const float* __restrict__ Wr,
                             u16* __restrict__ WtH, u16* __restrict__ WtL) {
    int idx = blockIdx.x * blockDim.x + threadIdx.x;
    if (idx >= 512 * 256) return;
    int n = idx >> 8, k = idx & 255;
    float w = (n < 256) ? Wl[k * 256 + n] : Wr[k * 256 + (n - 256)];
    u16 h = f2bf(w);
    WtH[idx] = h;
    WtL[idx] = f2bf(w - bf2f(h));
}

__global__ void prep_w_fc(const float* __restrict__ Wfc,
                          u16* __restrict__ WtH, u16* __restrict__ WtL) {
    int idx = blockIdx.x * blockDim.x + threadIdx.x;
    if (idx >= 128 * 256) return;
    int n = idx >> 8, k = idx & 255;
    float w = Wfc[k * 128 + n];
    u16 h = f2bf(w);
    WtH[idx] = h;
    WtL[idx] = f2bf(w - bf2f(h));
}

// ---------------- 3-term split-precision bf16 MFMA GEMM ----------------
__global__ __launch_bounds__(256) void gemm3(
        const u16* __restrict__ Ah, const u16* __restrict__ Al,
        const u16* __restrict__ WtH, const u16* __restrict__ WtL,
        const float* __restrict__ bias0, const float* __restrict__ bias1,
        float* __restrict__ C0, float* __restrict__ C1, int ldc, int M) {
    __shared__ __align__(16) u16 lA[128 * 64];
    __shared__ __align__(16) u16 lB[128 * 64];

    int tid = threadIdx.x;
    int wid = tid >> 6, lane = tid & 63;
    int wm = wid >> 1, wn = wid & 1;
    int m0 = blockIdx.x * 128, n0 = blockIdx.y * 128;
    int lr = lane & 15, lk = lane >> 4;

    f32x4 acc[4][4] = {};

#pragma unroll 1
    for (int seg = 0; seg < 3; seg++) {
        const u16* As = (seg == 1) ? Al : Ah;
        const u16* Ws = (seg == 2) ? WtL : WtH;
#pragma unroll 1
        for (int k0 = 0; k0 < 256; k0 += 64) {
#pragma unroll
            for (int i = 0; i < 4; i++) {
                int t = i * 256 + tid;
                int row = t >> 3;
                int ch = (t & 7) ^ (row & 7);
                gload_lds16(As + (size_t)(m0 + row) * 256 + k0 + ch * 8,
                            (char*)lA + i * 4096 + wid * 1024);
            }
#pragma unroll
            for (int i = 0; i < 4; i++) {
                int t = i * 256 + tid;
                int row = t >> 3;
                int ch = (t & 7) ^ (row & 7);
                gload_lds16(Ws + (size_t)(n0 + row) * 256 + k0 + ch * 8,
                            (char*)lB + i * 4096 + wid * 1024);
            }
            __syncthreads();

#pragma unroll
            for (int kk = 0; kk < 2; kk++) {
                s16x8 af[4], bf[4];
#pragma unroll
                for (int mr = 0; mr < 4; mr++) {
                    int r = wm * 64 + mr * 16 + lr;
                    int q = (kk * 4 + lk) ^ (r & 7);
                    af[mr] = *(const s16x8*)&lA[r * 64 + q * 8];
                }
#pragma unroll
                for (int nr = 0; nr < 4; nr++) {
                    int r = wn * 64 + nr * 16 + lr;
                    int q = (kk * 4 + lk) ^ (r & 7);
                    bf[nr] = *(const s16x8*)&lB[r * 64 + q * 8];
                }
#pragma unroll
                for (int mr = 0; mr < 4; mr++)
#pragma unroll
                    for (int nr = 0; nr < 4; nr++)
                        acc[mr][nr] = __builtin_amdgcn_mfma_f32_16x16x32_bf16(
                            af[mr], bf[nr], acc[mr][nr], 0, 0, 0);
            }
            __syncthreads();
        }
    }

#pragma unroll
    for (int mr = 0; mr < 4; mr++) {
#pragma unroll
        for (int nr = 0; nr < 4; nr++) {
            int col = n0 + wn * 64 + nr * 16 + lr;
            float* Cp; const float* bp; int c;
            if (col < 256) { Cp = C0; bp = bias0; c = col; }
            else           { Cp = C1; bp = bias1; c = col - 256; }
            float b = bp[c];
#pragma unroll
            for (int j = 0; j < 4; j++) {
                int row = m0 + wm * 64 + mr * 16 + lk * 4 + j;
                if (row < M) Cp[(size_t)row * ldc + c] = acc[mr][nr][j] + b;
            }
        }
    }
}

// ---------------- CSR build ----------------
__global__ void count_deg(const int* __restrict__ dstA, int* __restrict__ deg) {
    int i = blockIdx.x * blockDim.x + threadIdx.x;
    int stride = gridDim.x * blockDim.x;
    for (; i < N_EDGES; i += stride) atomicAdd(&deg[dstA[i]], 1);
}

__global__ void scan_phase1(const int* __restrict__ deg, int* __restrict__ blocksum) {
    __shared__ int sdata[SCAN_BLOCK];
    int i = blockIdx.x * SCAN_BLOCK + threadIdx.x;
    sdata[threadIdx.x] = (i < N_NODES) ? deg[i] : 0;
    __syncthreads();
    for (int off = SCAN_BLOCK / 2; off > 0; off >>= 1) {
        if (threadIdx.x < off) sdata[threadIdx.x] += sdata[threadIdx.x + off];
        __syncthreads();
    }
    if (threadIdx.x == 0) blocksum[blockIdx.x] = sdata[0];
}

__global__ void scan_phase2(int* __restrict__ blocksum) {
    __shared__ int part[512];
    int t = threadIdx.x;
    int v = (t < SCAN_NBLK) ? blocksum[t] : 0;
    part[t] = v;
    __syncthreads();
    for (int off = 1; off < 512; off <<= 1) {
        int u = 0;
        if (t >= off) u = part[t - off];
        __syncthreads();
        if (t >= off) part[t] += u;
        __syncthreads();
    }
    if (t < SCAN_NBLK) blocksum[t] = part[t] - v;   // exclusive
}

__global__ void scan_phase3(const int* __restrict__ deg, const int* __restrict__ blockoff,
                            int* __restrict__ rowstart, int* __restrict__ cursor) {
    __shared__ int part[SCAN_BLOCK];
    int t = threadIdx.x;
    int i = blockIdx.x * SCAN_BLOCK + t;
    int v = (i < N_NODES) ? deg[i] : 0;
    part[t] = v;
    __syncthreads();
    for (int off = 1; off < SCAN_BLOCK; off <<= 1) {
        int u = 0;
        if (t >= off) u = part[t - off];
        __syncthreads();
        if (t >= off) part[t] += u;
        __syncthreads();
    }
    if (i < N_NODES) {
        int excl = blockoff[blockIdx.x] + part[t] - v;
        rowstart[i] = excl;
        cursor[i] = excl;
        if (i == N_NODES - 1) rowstart[N_NODES] = blockoff[blockIdx.x] + part[t];
    }
}

__global__ void fill_csr(const int* __restrict__ srcA, const int* __restrict__ dstA,
                         int* __restrict__ cursor, int* __restrict__ csr_src) {
    int i = blockIdx.x * blockDim.x + threadIdx.x;
    int stride = gridDim.x * blockDim.x;
    for (; i < N_EDGES; i += stride) {
        int pos = atomicAdd(&cursor[dstA[i]], 1);
        csr_src[pos] = srcA[i];
    }
}

// ---------------- Fused GATv2 edge phase (one wave per destination) ----------------
// float4-per-lane layout: lane owns cols 4*lane..4*lane+3; head = lane>>3.
// One dwordx4 load per edge row; 3-shfl reduce within 8-lane head group.
__global__ void gat_fused(const float* __restrict__ xl, const float* __restrict__ xr,
                          const int* __restrict__ rowstart, const int* __restrict__ csr_src,
                          const float* __restrict__ att, float* __restrict__ out) {
    int wid = (blockIdx.x * blockDim.x + threadIdx.x) >> 6;
    int lane = threadIdx.x & 63;
    if (wid >= N_NODES) return;

    f32x4 xrv  = *(const f32x4*)(xr + (size_t)wid * FDIM + lane * 4);
    f32x4 attv = *(const f32x4*)(att + lane * 4);
    f32x4 acc = {0.f, 0.f, 0.f, 0.f};
    float den = 0.f;

    int jb = rowstart[wid], je = rowstart[wid + 1];
    if (jb < je) {
        f32x4 xv = *(const f32x4*)(xl + (size_t)csr_src[jb] * FDIM + lane * 4);
        for (int j = jb; j < je; ++j) {
            int j2 = (j + 1 < je) ? j + 1 : j;
            f32x4 nxt = *(const f32x4*)(xl + (size_t)csr_src[j2] * FDIM + lane * 4);

            float s = 0.f;
#pragma unroll
            for (int i = 0; i < 4; i++) {
                float v = xv[i] + xrv[i];
                v = v > 0.f ? v : 0.2f * v;
                s += v * attv[i];
            }
            // reduce over the 8-lane head group (head = lane>>3)
            s += __shfl_xor(s, 1);
            s += __shfl_xor(s, 2);
            s += __shfl_xor(s, 4);
            float e = __expf(s);
            den += e;
#pragma unroll
            for (int i = 0; i < 4; i++) acc[i] += e * xv[i];
            xv = nxt;
        }
    }
    float inv = 1.f / (den + 1e-16f);
    f32x4 o;
#pragma unroll
    for (int i = 0; i < 4; i++) o[i] = acc[i] * inv;
    *(f32x4*)(out + (size_t)wid * FDIM + lane * 4) = o;
}

// ---------------- BatchNorm ----------------
__global__ void bn_stats(const float* __restrict__ X, float* __restrict__ sum,
                         float* __restrict__ sumsq, int nrows) {
    int col = threadIdx.x;
    float s = 0.f, ss = 0.f;
    for (int r = blockIdx.x; r < nrows; r += gridDim.x) {
        float v = X[(size_t)r * FDIM + col];
        s += v;
        ss += v * v;
    }
    atomicAdd(&sum[col], s);
    atomicAdd(&sumsq[col], ss);
}

__global__ void bn_finalize(const float* __restrict__ sum, const float* __restrict__ sumsq,
                            const float* __restrict__ gamma, const float* __restrict__ beta,
                            float* __restrict__ scale, float* __restrict__ shift) {
    int c = threadIdx.x;
    float mean = sum[c] * (1.f / N_NODES);
    float var = sumsq[c] * (1.f / N_NODES) - mean * mean;
    float sc = gamma[c] * rsqrtf(var + 1e-5f);
    scale[c] = sc;
    shift[c] = beta[c] - mean * sc;
}

// BN + ELU fused, output split to bf16 hi/lo (pad rows zeroed)
__global__ void bn_elu_split(const float* __restrict__ X, const float* __restrict__ scale,
                             const float* __restrict__ shift,
                             u16* __restrict__ hi, u16* __restrict__ lo) {
    int i = blockIdx.x * blockDim.x + threadIdx.x;   // float4 units
    int stride = gridDim.x * blockDim.x;
    const int n_valid4 = N_NODES * FDIM / 4;
    const int n_pad4 = NPAD * FDIM / 4;
    for (; i < n_pad4; i += stride) {
        u16 h[4], l[4];
        if (i < n_valid4) {
            f32x4 v = ((const f32x4*)X)[i];
            int c0 = (i * 4) & (FDIM - 1);
#pragma unroll
            for (int j = 0; j < 4; j++) {
                float f = v[j] * scale[c0 + j] + shift[c0 + j];
                f = f > 0.f ? f : expf(f) - 1.f;
                h[j] = f2bf(f);
                l[j] = f2bf(f - bf2f(h[j]));
            }
        } else {
#pragma unroll
            for (int j = 0; j < 4; j++) { h[j] = 0; l[j] = 0; }
        }
        ((ushort4*)hi)[i] = make_ushort4(h[0], h[1], h[2], h[3]);
        ((ushort4*)lo)[i] = make_ushort4(l[0], l[1], l[2], l[3]);
    }
}

// ---------------- Row L2 normalize ----------------
__global__ void l2norm(float* __restrict__ Y, int nrows) {
    int gtid = blockIdx.x * blockDim.x + threadIdx.x;
    int wave = gtid >> 6;
    int lane = threadIdx.x & 63;
    int nwaves = (gridDim.x * blockDim.x) >> 6;
    for (int r = wave; r < nrows; r += nwaves) {
        float v0 = Y[(size_t)r * OUTF + lane];
        float v1 = Y[(size_t)r * OUTF + 64 + lane];
        float ss = v0 * v0 + v1 * v1;
        ss += __shfl_xor(ss, 32);
        ss += __shfl_xor(ss, 16);
        ss += __shfl_xor(ss, 8);
        ss += __shfl_xor(ss, 4);
        ss += __shfl_xor(ss, 2);
        ss += __shfl_xor(ss, 1);
        float inv = 1.f / fmaxf(sqrtf(ss), 1e-12f);
        Y[(size_t)r * OUTF + lane] = v0 * inv;
        Y[(size_t)r * OUTF + 64 + lane] = v1 * inv;
    }
}

extern "C" void kernel_launch(void* const* d_in, const int* in_sizes, int n_in,
                              void* d_out, int out_size, void* d_ws, size_t ws_size,
                              hipStream_t stream) {
    const float* x     = (const float*)d_in[0];
    const int*   ei    = (const int*)d_in[1];
    const float* Wl1   = (const float*)d_in[2];
    const float* bl1   = (const float*)d_in[3];
    const float* Wr1   = (const float*)d_in[4];
    const float* br1   = (const float*)d_in[5];
    const float* att1  = (const float*)d_in[6];
    // d_in[7] = bias1 : cancels exactly inside batchnorm -> skipped
    const float* gamma1 = (const float*)d_in[8];
    const float* beta1  = (const float*)d_in[9];
    const float* Wl2   = (const float*)d_in[10];
    const float* bl2   = (const float*)d_in[11];
    const float* Wr2   = (const float*)d_in[12];
    const float* br2   = (const float*)d_in[13];
    const float* att2  = (const float*)d_in[14];
    // d_in[15] = bias2 : cancels inside batchnorm -> skipped
    const float* gamma2 = (const float*)d_in[16];
    const float* beta2  = (const float*)d_in[17];
    const float* Wfc   = (const float*)d_in[18];
    const float* bfc   = (const float*)d_in[19];

    const int* srcA = ei;
    const int* dstA = ei + N_EDGES;

    const size_t REG = (size_t)NPAD * FDIM * 4;
    char* p = (char*)d_ws;
    char* R0 = p;            p += REG;
    char* R1 = p;            p += REG;
    char* R2 = p;            p += REG;
    u16* WTH   = (u16*)p;              p += 512 * 256 * 2;
    u16* WTL   = (u16*)p;              p += 512 * 256 * 2;
    float* SUM = (float*)p;            p += FDIM * 4;
    float* SQ  = (float*)p;            p += FDIM * 4;
    float* SC  = (float*)p;            p += FDIM * 4;
    float* SH  = (float*)p;            p += FDIM * 4;
    int* DEG      = (int*)p;           p += (size_t)N_NODES * 4;
    int* ROWSTART = (int*)p;           p += (size_t)(N_NODES + 1) * 4;
    int* CURSOR   = (int*)p;           p += (size_t)N_NODES * 4;
    int* CSR      = (int*)p;           p += (size_t)N_EDGES * 4;
    int* BLKSUM   = (int*)p;           p += (size_t)SCAN_NBLK * 4;

    const size_t HALF = (size_t)NPAD * FDIM;  // u16 elements per half-region

    const int gat_grid = (N_NODES + 3) / 4;
    const dim3 gemm_grid_layer(NPAD / 128, 4);
    const dim3 gemm_grid_fc(NPAD / 128, 1);

    // ---------------- CSR build ----------------
    hipMemsetAsync(DEG, 0, (size_t)N_NODES * sizeof(int), stream);
    count_deg<<<2048, 256, 0, stream>>>(dstA, DEG);
    scan_phase1<<<SCAN_NBLK, SCAN_BLOCK, 0, stream>>>(DEG, BLKSUM);
    scan_phase2<<<1, 512, 0, stream>>>(BLKSUM);
    scan_phase3<<<SCAN_NBLK, SCAN_BLOCK, 0, stream>>>(DEG, BLKSUM, ROWSTART, CURSOR);
    fill_csr<<<2048, 256, 0, stream>>>(srcA, dstA, CURSOR, CSR);

    // ---------------- Layer 1 ----------------
    split_hilo<<<4096, 256, 0, stream>>>(x, N_NODES * FDIM / 4, NPAD * FDIM / 4,
                                         (u16*)R0, (u16*)R0 + HALF);
    prep_w_layer<<<512, 256, 0, stream>>>(Wl1, Wr1, WTH, WTL);
    gemm3<<<gemm_grid_layer, 256, 0, stream>>>((u16*)R0, (u16*)R0 + HALF, WTH, WTL,
                                               bl1, br1, (float*)R1, (float*)R2, 256, N_NODES);
    gat_fused<<<gat_grid, 256, 0, stream>>>((float*)R1, (float*)R2, ROWSTART, CSR, att1, (float*)R0);

    hipMemsetAsync(SUM, 0, 2 * FDIM * sizeof(float), stream);
    bn_stats<<<1024, 256, 0, stream>>>((float*)R0, SUM, SQ, N_NODES);
    bn_finalize<<<1, 256, 0, stream>>>(SUM, SQ, gamma1, beta1, SC, SH);
    bn_elu_split<<<4096, 256, 0, stream>>>((float*)R0, SC, SH, (u16*)R1, (u16*)R1 + HALF);

    // ---------------- Layer 2 ----------------
    prep_w_layer<<<512, 256, 0, stream>>>(Wl2, Wr2, WTH, WTL);
    gemm3<<<gemm_grid_layer, 256, 0, stream>>>((u16*)R1, (u16*)R1 + HALF, WTH, WTL,
                                               bl2, br2, (float*)R2, (float*)R0, 256, N_NODES);
    gat_fused<<<gat_grid, 256, 0, stream>>>((float*)R2, (float*)R0, ROWSTART, CSR, att2, (float*)R1);

    hipMemsetAsync(SUM, 0, 2 * FDIM * sizeof(float), stream);
    bn_stats<<<1024, 256, 0, stream>>>((float*)R1, SUM, SQ, N_NODES);
    bn_finalize<<<1, 256, 0, stream>>>(SUM, SQ, gamma2, beta2, SC, SH);
    bn_elu_split<<<4096, 256, 0, stream>>>((float*)R1, SC, SH, (u16*)R2, (u16*)R2 + HALF);

    // ---------------- FC + L2 normalize ----------------
    prep_w_fc<<<128, 256, 0, stream>>>(Wfc, WTH, WTL);
    gemm3<<<gemm_grid_fc, 256, 0, stream>>>((u16*)R2, (u16*)R2 + HALF, WTH, WTL,
                                            bfc, bfc, (float*)d_out, (float*)d_out, 128, N_NODES);
    l2norm<<<2048, 256, 0, stream>>>((float*)d_out, N_NODES);
}

// Round 8
// 937.117 us; speedup vs baseline: 3.5157x; 1.0193x over previous
//
#include <hip/hip_runtime.h>
#include <math.h>

#define N_NODES 100000
#define N_EDGES 800000
#define NPAD    100096   // 782 * 128
#define FDIM 256
#define HEADS 8
#define CDIM 32
#define OUTF 128

#define SCAN_BLOCK 256
#define SCAN_NBLK ((N_NODES + SCAN_BLOCK - 1) / SCAN_BLOCK)   // 391

typedef short  s16x8 __attribute__((ext_vector_type(8)));
typedef float  f32x4 __attribute__((ext_vector_type(4)));
typedef unsigned short u16;

__device__ __forceinline__ u16 f2bf(float f) {
    unsigned u = __float_as_uint(f);
    unsigned r = (u + 0x7fff + ((u >> 16) & 1)) >> 16;
    return (u16)r;
}
__device__ __forceinline__ float bf2f(u16 h) {
    return __uint_as_float(((unsigned)h) << 16);
}

__device__ __forceinline__ void gload_lds16(const void* g, void* l) {
    __builtin_amdgcn_global_load_lds((const __attribute__((address_space(1))) void*)g,
                                     (__attribute__((address_space(3))) void*)l, 16, 0, 0);
}

// ---------------- split f32 -> bf16 hi/lo (pad region zeroed) ----------------
__global__ void split_hilo(const float* __restrict__ src, int n_valid4, int n_pad4,
                           u16* __restrict__ hi, u16* __restrict__ lo) {
    int i = blockIdx.x * blockDim.x + threadIdx.x;
    int stride = gridDim.x * blockDim.x;
    for (; i < n_pad4; i += stride) {
        f32x4 v = {0.f, 0.f, 0.f, 0.f};
        if (i < n_valid4) v = ((const f32x4*)src)[i];
        u16 h[4], l[4];
#pragma unroll
        for (int j = 0; j < 4; j++) {
            float f = v[j];
            h[j] = f2bf(f);
            l[j] = f2bf(f - bf2f(h[j]));
        }
        ((ushort4*)hi)[i] = make_ushort4(h[0], h[1], h[2], h[3]);
        ((ushort4*)lo)[i] = make_ushort4(l[0], l[1], l[2], l[3]);
    }
}

// ---------------- W prep: transpose + concat + split ----------------
__global__ void prep_w_layer(const float* __restrict__ Wl, const float* __restrict__ Wr,
                             u16* __restrict__ WtH, u16* __restrict__ WtL) {
    int idx = blockIdx.x * blockDim.x + threadIdx.x;
    if (idx >= 512 * 256) return;
    int n = idx >> 8, k = idx & 255;
    float w = (n < 256) ? Wl[k * 256 + n] : Wr[k * 256 + (n - 256)];
    u16 h = f2bf(w);
    WtH[idx] = h;
    WtL[idx] = f2bf(w - bf2f(h));
}

__global__ void prep_w_fc(const float* __restrict__ Wfc,
                          u16* __restrict__ WtH, u16* __restrict__ WtL) {
    int idx = blockIdx.x * blockDim.x + threadIdx.x;
    if (idx >= 128 * 256) return;
    int n = idx >> 8, k = idx & 255;
    float w = Wfc[k * 128 + n];
    u16 h = f2bf(w);
    WtH[idx] = h;
    WtL[idx] = f2bf(w - bf2f(h));
}

// ---------------- 3-term split-precision bf16 MFMA GEMM ----------------
__global__ __launch_bounds__(256) void gemm3(
        const u16* __restrict__ Ah, const u16* __restrict__ Al,
        const u16* __restrict__ WtH, const u16* __restrict__ WtL,
        const float* __restrict__ bias0, const float* __restrict__ bias1,
        float* __restrict__ C0, float* __restrict__ C1, int ldc, int M) {
    __shared__ __align__(16) u16 lA[128 * 64];
    __shared__ __align__(16) u16 lB[128 * 64];

    int tid = threadIdx.x;
    int wid = tid >> 6, lane = tid & 63;
    int wm = wid >> 1, wn = wid & 1;
    int m0 = blockIdx.x * 128, n0 = blockIdx.y * 128;
    int lr = lane & 15, lk = lane >> 4;

    f32x4 acc[4][4] = {};

#pragma unroll 1
    for (int seg = 0; seg < 3; seg++) {
        const u16* As = (seg == 1) ? Al : Ah;
        const u16* Ws = (seg == 2) ? WtL : WtH;
#pragma unroll 1
        for (int k0 = 0; k0 < 256; k0 += 64) {
#pragma unroll
            for (int i = 0; i < 4; i++) {
                int t = i * 256 + tid;
                int row = t >> 3;
                int ch = (t & 7) ^ (row & 7);
                gload_lds16(As + (size_t)(m0 + row) * 256 + k0 + ch * 8,
                            (char*)lA + i * 4096 + wid * 1024);
            }
#pragma unroll
            for (int i = 0; i < 4; i++) {
                int t = i * 256 + tid;
                int row = t >> 3;
                int ch = (t & 7) ^ (row & 7);
                gload_lds16(Ws + (size_t)(n0 + row) * 256 + k0 + ch * 8,
                            (char*)lB + i * 4096 + wid * 1024);
            }
            __syncthreads();

#pragma unroll
            for (int kk = 0; kk < 2; kk++) {
                s16x8 af[4], bf[4];
#pragma unroll
                for (int mr = 0; mr < 4; mr++) {
                    int r = wm * 64 + mr * 16 + lr;
                    int q = (kk * 4 + lk) ^ (r & 7);
                    af[mr] = *(const s16x8*)&lA[r * 64 + q * 8];
                }
#pragma unroll
                for (int nr = 0; nr < 4; nr++) {
                    int r = wn * 64 + nr * 16 + lr;
                    int q = (kk * 4 + lk) ^ (r & 7);
                    bf[nr] = *(const s16x8*)&lB[r * 64 + q * 8];
                }
#pragma unroll
                for (int mr = 0; mr < 4; mr++)
#pragma unroll
                    for (int nr = 0; nr < 4; nr++)
                        acc[mr][nr] = __builtin_amdgcn_mfma_f32_16x16x32_bf16(
                            af[mr], bf[nr], acc[mr][nr], 0, 0, 0);
            }
            __syncthreads();
        }
    }

#pragma unroll
    for (int mr = 0; mr < 4; mr++) {
#pragma unroll
        for (int nr = 0; nr < 4; nr++) {
            int col = n0 + wn * 64 + nr * 16 + lr;
            float* Cp; const float* bp; int c;
            if (col < 256) { Cp = C0; bp = bias0; c = col; }
            else           { Cp = C1; bp = bias1; c = col - 256; }
            float b = bp[c];
#pragma unroll
            for (int j = 0; j < 4; j++) {
                int row = m0 + wm * 64 + mr * 16 + lk * 4 + j;
                if (row < M) Cp[(size_t)row * ldc + c] = acc[mr][nr][j] + b;
            }
        }
    }
}

// ---------------- CSR build ----------------
__global__ void count_deg(const int* __restrict__ dstA, int* __restrict__ deg) {
    int i = blockIdx.x * blockDim.x + threadIdx.x;
    int stride = gridDim.x * blockDim.x;
    for (; i < N_EDGES; i += stride) atomicAdd(&deg[dstA[i]], 1);
}

__global__ void scan_phase1(const int* __restrict__ deg, int* __restrict__ blocksum) {
    __shared__ int sdata[SCAN_BLOCK];
    int i = blockIdx.x * SCAN_BLOCK + threadIdx.x;
    sdata[threadIdx.x] = (i < N_NODES) ? deg[i] : 0;
    __syncthreads();
    for (int off = SCAN_BLOCK / 2; off > 0; off >>= 1) {
        if (threadIdx.x < off) sdata[threadIdx.x] += sdata[threadIdx.x + off];
        __syncthreads();
    }
    if (threadIdx.x == 0) blocksum[blockIdx.x] = sdata[0];
}

__global__ void scan_phase2(int* __restrict__ blocksum) {
    __shared__ int part[512];
    int t = threadIdx.x;
    int v = (t < SCAN_NBLK) ? blocksum[t] : 0;
    part[t] = v;
    __syncthreads();
    for (int off = 1; off < 512; off <<= 1) {
        int u = 0;
        if (t >= off) u = part[t - off];
        __syncthreads();
        if (t >= off) part[t] += u;
        __syncthreads();
    }
    if (t < SCAN_NBLK) blocksum[t] = part[t] - v;   // exclusive
}

__global__ void scan_phase3(const int* __restrict__ deg, const int* __restrict__ blockoff,
                            int* __restrict__ rowstart, int* __restrict__ cursor) {
    __shared__ int part[SCAN_BLOCK];
    int t = threadIdx.x;
    int i = blockIdx.x * SCAN_BLOCK + t;
    int v = (i < N_NODES) ? deg[i] : 0;
    part[t] = v;
    __syncthreads();
    for (int off = 1; off < SCAN_BLOCK; off <<= 1) {
        int u = 0;
        if (t >= off) u = part[t - off];
        __syncthreads();
        if (t >= off) part[t] += u;
        __syncthreads();
    }
    if (i < N_NODES) {
        int excl = blockoff[blockIdx.x] + part[t] - v;
        rowstart[i] = excl;
        cursor[i] = excl;
        if (i == N_NODES - 1) rowstart[N_NODES] = blockoff[blockIdx.x] + part[t];
    }
}

__global__ void fill_csr(const int* __restrict__ srcA, const int* __restrict__ dstA,
                         int* __restrict__ cursor, int* __restrict__ csr_src) {
    int i = blockIdx.x * blockDim.x + threadIdx.x;
    int stride = gridDim.x * blockDim.x;
    for (; i < N_EDGES; i += stride) {
        int pos = atomicAdd(&cursor[dstA[i]], 1);
        csr_src[pos] = srcA[i];
    }
}

// ---------------- Fused GATv2 edge phase (one wave per destination) ----------------
// float4-per-lane layout; depth-2 software pipeline on the row gathers.
__global__ void gat_fused(const float* __restrict__ xl, const float* __restrict__ xr,
                          const int* __restrict__ rowstart, const int* __restrict__ csr_src,
                          const float* __restrict__ att, float* __restrict__ out) {
    int wid = (blockIdx.x * blockDim.x + threadIdx.x) >> 6;
    int lane = threadIdx.x & 63;
    if (wid >= N_NODES) return;

    f32x4 xrv  = *(const f32x4*)(xr + (size_t)wid * FDIM + lane * 4);
    f32x4 attv = *(const f32x4*)(att + lane * 4);
    f32x4 acc = {0.f, 0.f, 0.f, 0.f};
    float den = 0.f;

    int jb = rowstart[wid], je = rowstart[wid + 1];
    if (jb < je) {
        int jlast = je - 1;
        // pipeline depth 2: hold rows j and j+1, load j+2
        f32x4 xv0 = *(const f32x4*)(xl + (size_t)csr_src[jb] * FDIM + lane * 4);
        int j1 = (jb + 1 <= jlast) ? jb + 1 : jlast;
        f32x4 xv1 = *(const f32x4*)(xl + (size_t)csr_src[j1] * FDIM + lane * 4);

        for (int j = jb; j < je; ++j) {
            int j2 = (j + 2 <= jlast) ? j + 2 : jlast;
            f32x4 nxt = *(const f32x4*)(xl + (size_t)csr_src[j2] * FDIM + lane * 4);

            float s = 0.f;
#pragma unroll
            for (int i = 0; i < 4; i++) {
                float v = xv0[i] + xrv[i];
                v = v > 0.f ? v : 0.2f * v;
                s += v * attv[i];
            }
            // reduce over the 8-lane head group (head = lane>>3)
            s += __shfl_xor(s, 1);
            s += __shfl_xor(s, 2);
            s += __shfl_xor(s, 4);
            float e = __expf(s);
            den += e;
#pragma unroll
            for (int i = 0; i < 4; i++) acc[i] += e * xv0[i];
            xv0 = xv1;
            xv1 = nxt;
        }
    }
    float inv = 1.f / (den + 1e-16f);
    f32x4 o;
#pragma unroll
    for (int i = 0; i < 4; i++) o[i] = acc[i] * inv;
    *(f32x4*)(out + (size_t)wid * FDIM + lane * 4) = o;
}

// ---------------- BatchNorm ----------------
__global__ void bn_stats(const float* __restrict__ X, float* __restrict__ sum,
                         float* __restrict__ sumsq, int nrows) {
    int col = threadIdx.x;
    float s = 0.f, ss = 0.f;
    for (int r = blockIdx.x; r < nrows; r += gridDim.x) {
        float v = X[(size_t)r * FDIM + col];
        s += v;
        ss += v * v;
    }
    atomicAdd(&sum[col], s);
    atomicAdd(&sumsq[col], ss);
}

__global__ void bn_finalize(const float* __restrict__ sum, const float* __restrict__ sumsq,
                            const float* __restrict__ gamma, const float* __restrict__ beta,
                            float* __restrict__ scale, float* __restrict__ shift) {
    int c = threadIdx.x;
    float mean = sum[c] * (1.f / N_NODES);
    float var = sumsq[c] * (1.f / N_NODES) - mean * mean;
    float sc = gamma[c] * rsqrtf(var + 1e-5f);
    scale[c] = sc;
    shift[c] = beta[c] - mean * sc;
}

// BN + ELU fused, output split to bf16 hi/lo (pad rows zeroed)
__global__ void bn_elu_split(const float* __restrict__ X, const float* __restrict__ scale,
                             const float* __restrict__ shift,
                             u16* __restrict__ hi, u16* __restrict__ lo) {
    int i = blockIdx.x * blockDim.x + threadIdx.x;   // float4 units
    int stride = gridDim.x * blockDim.x;
    const int n_valid4 = N_NODES * FDIM / 4;
    const int n_pad4 = NPAD * FDIM / 4;
    for (; i < n_pad4; i += stride) {
        u16 h[4], l[4];
        if (i < n_valid4) {
            f32x4 v = ((const f32x4*)X)[i];
            int c0 = (i * 4) & (FDIM - 1);
#pragma unroll
            for (int j = 0; j < 4; j++) {
                float f = v[j] * scale[c0 + j] + shift[c0 + j];
                f = f > 0.f ? f : expf(f) - 1.f;
                h[j] = f2bf(f);
                l[j] = f2bf(f - bf2f(h[j]));
            }
        } else {
#pragma unroll
            for (int j = 0; j < 4; j++) { h[j] = 0; l[j] = 0; }
        }
        ((ushort4*)hi)[i] = make_ushort4(h[0], h[1], h[2], h[3]);
        ((ushort4*)lo)[i] = make_ushort4(l[0], l[1], l[2], l[3]);
    }
}

// ---------------- Row L2 normalize ----------------
__global__ void l2norm(float* __restrict__ Y, int nrows) {
    int gtid = blockIdx.x * blockDim.x + threadIdx.x;
    int wave = gtid >> 6;
    int lane = threadIdx.x & 63;
    int nwaves = (gridDim.x * blockDim.x) >> 6;
    for (int r = wave; r < nrows; r += nwaves) {
        float v0 = Y[(size_t)r * OUTF + lane];
        float v1 = Y[(size_t)r * OUTF + 64 + lane];
        float ss = v0 * v0 + v1 * v1;
        ss += __shfl_xor(ss, 32);
        ss += __shfl_xor(ss, 16);
        ss += __shfl_xor(ss, 8);
        ss += __shfl_xor(ss, 4);
        ss += __shfl_xor(ss, 2);
        ss += __shfl_xor(ss, 1);
        float inv = 1.f / fmaxf(sqrtf(ss), 1e-12f);
        Y[(size_t)r * OUTF + lane] = v0 * inv;
        Y[(size_t)r * OUTF + 64 + lane] = v1 * inv;
    }
}

extern "C" void kernel_launch(void* const* d_in, const int* in_sizes, int n_in,
                              void* d_out, int out_size, void* d_ws, size_t ws_size,
                              hipStream_t stream) {
    const float* x     = (const float*)d_in[0];
    const int*   ei    = (const int*)d_in[1];
    const float* Wl1   = (const float*)d_in[2];
    const float* bl1   = (const float*)d_in[3];
    const float* Wr1   = (const float*)d_in[4];
    const float* br1   = (const float*)d_in[5];
    const float* att1  = (const float*)d_in[6];
    // d_in[7] = bias1 : cancels exactly inside batchnorm -> skipped
    const float* gamma1 = (const float*)d_in[8];
    const float* beta1  = (const float*)d_in[9];
    const float* Wl2   = (const float*)d_in[10];
    const float* bl2   = (const float*)d_in[11];
    const float* Wr2   = (const float*)d_in[12];
    const float* br2   = (const float*)d_in[13];
    const float* att2  = (const float*)d_in[14];
    // d_in[15] = bias2 : cancels inside batchnorm -> skipped
    const float* gamma2 = (const float*)d_in[16];
    const float* beta2  = (const float*)d_in[17];
    const float* Wfc   = (const float*)d_in[18];
    const float* bfc   = (const float*)d_in[19];

    const int* srcA = ei;
    const int* dstA = ei + N_EDGES;

    const size_t REG = (size_t)NPAD * FDIM * 4;
    char* p = (char*)d_ws;
    char* R0 = p;            p += REG;
    char* R1 = p;            p += REG;
    char* R2 = p;            p += REG;
    u16* WTH   = (u16*)p;              p += 512 * 256 * 2;
    u16* WTL   = (u16*)p;              p += 512 * 256 * 2;
    float* SUM = (float*)p;            p += FDIM * 4;
    float* SQ  = (float*)p;            p += FDIM * 4;
    float* SC  = (float*)p;            p += FDIM * 4;
    float* SH  = (float*)p;            p += FDIM * 4;
    int* DEG      = (int*)p;           p += (size_t)N_NODES * 4;
    int* ROWSTART = (int*)p;           p += (size_t)(N_NODES + 1) * 4;
    int* CURSOR   = (int*)p;           p += (size_t)N_NODES * 4;
    int* CSR      = (int*)p;           p += (size_t)N_EDGES * 4;
    int* BLKSUM   = (int*)p;           p += (size_t)SCAN_NBLK * 4;

    const size_t HALF = (size_t)NPAD * FDIM;  // u16 elements per half-region

    const int gat_grid = (N_NODES + 3) / 4;
    const dim3 gemm_grid_layer(NPAD / 128, 4);
    const dim3 gemm_grid_fc(NPAD / 128, 1);

    // ---------------- CSR build ----------------
    hipMemsetAsync(DEG, 0, (size_t)N_NODES * sizeof(int), stream);
    count_deg<<<2048, 256, 0, stream>>>(dstA, DEG);
    scan_phase1<<<SCAN_NBLK, SCAN_BLOCK, 0, stream>>>(DEG, BLKSUM);
    scan_phase2<<<1, 512, 0, stream>>>(BLKSUM);
    scan_phase3<<<SCAN_NBLK, SCAN_BLOCK, 0, stream>>>(DEG, BLKSUM, ROWSTART, CURSOR);
    fill_csr<<<2048, 256, 0, stream>>>(srcA, dstA, CURSOR, CSR);

    // ---------------- Layer 1 ----------------
    split_hilo<<<4096, 256, 0, stream>>>(x, N_NODES * FDIM / 4, NPAD * FDIM / 4,
                                         (u16*)R0, (u16*)R0 + HALF);
    prep_w_layer<<<512, 256, 0, stream>>>(Wl1, Wr1, WTH, WTL);
    gemm3<<<gemm_grid_layer, 256, 0, stream>>>((u16*)R0, (u16*)R0 + HALF, WTH, WTL,
                                               bl1, br1, (float*)R1, (float*)R2, 256, N_NODES);
    gat_fused<<<gat_grid, 256, 0, stream>>>((float*)R1, (float*)R2, ROWSTART, CSR, att1, (float*)R0);

    hipMemsetAsync(SUM, 0, 2 * FDIM * sizeof(float), stream);
    bn_stats<<<1024, 256, 0, stream>>>((float*)R0, SUM, SQ, N_NODES);
    bn_finalize<<<1, 256, 0, stream>>>(SUM, SQ, gamma1, beta1, SC, SH);
    bn_elu_split<<<4096, 256, 0, stream>>>((float*)R0, SC, SH, (u16*)R1, (u16*)R1 + HALF);

    // ---------------- Layer 2 ----------------
    prep_w_layer<<<512, 256, 0, stream>>>(Wl2, Wr2, WTH, WTL);
    gemm3<<<gemm_grid_layer, 256, 0, stream>>>((u16*)R1, (u16*)R1 + HALF, WTH, WTL,
                                               bl2, br2, (float*)R2, (float*)R0, 256, N_NODES);
    gat_fused<<<gat_grid, 256, 0, stream>>>((float*)R2, (float*)R0, ROWSTART, CSR, att2, (float*)R1);

    hipMemsetAsync(SUM, 0, 2 * FDIM * sizeof(float), stream);
    bn_stats<<<1024, 256, 0, stream>>>((float*)R1, SUM, SQ, N_NODES);
    bn_finalize<<<1, 256, 0, stream>>>(SUM, SQ, gamma2, beta2, SC, SH);
    bn_elu_split<<<4096, 256, 0, stream>>>((float*)R1, SC, SH, (u16*)R2, (u16*)R2 + HALF);

    // ---------------- FC + L2 normalize ----------------
    prep_w_fc<<<128, 256, 0, stream>>>(Wfc, WTH, WTL);
    gemm3<<<gemm_grid_fc, 256, 0, stream>>>((u16*)R2, (u16*)R2 + HALF, WTH, WTL,
                                            bfc, bfc, (float*)d_out, (float*)d_out, 128, N_NODES);
    l2norm<<<2048, 256, 0, stream>>>((float*)d_out, N_NODES);
}